// Round 3
// baseline (1648.595 us; speedup 1.0000x reference)
//
#include <hip/hip_runtime.h>
#include <math.h>

#define NUM_HEADS 12
#define HEAD_DIM  64
#define HIDDEN    768
#define BS        8
#define FULL      240
#define SLOT_LEN  32
#define LEN0      512
#define LEN1      128
#define KTOT      672
#define M_TOK     (FULL * SLOT_LEN)   // 7680

typedef float f32x4 __attribute__((ext_vector_type(4)));
typedef short s16x8 __attribute__((ext_vector_type(8)));
typedef short s16x4 __attribute__((ext_vector_type(4)));

__device__ __forceinline__ short f2bf(float x) {
    unsigned u = __float_as_uint(x);
    unsigned r = (u + 0x7fffu + ((u >> 16) & 1u)) >> 16;
    return (short)r;
}

// async global->LDS, 16B per lane; lds base must be wave-uniform
__device__ __forceinline__ void gll16(const short* g, short* l) {
    __builtin_amdgcn_global_load_lds(
        (const __attribute__((address_space(1))) unsigned int*)g,
        (__attribute__((address_space(3))) unsigned int*)l, 16, 0, 0);
}

// ---------------------------------------------------------------------------
__global__ __launch_bounds__(256) void cast_hs(const float* __restrict__ in,
                                               short* __restrict__ out, int n4) {
    int i = blockIdx.x * 256 + threadIdx.x;
    if (i < n4) {
        float4 v = ((const float4*)in)[i];
        s16x4 o = {f2bf(v.x), f2bf(v.y), f2bf(v.z), f2bf(v.w)};
        ((s16x4*)out)[i] = o;
    }
}

// ---------------------------------------------------------------------------
// cache0_value -> bf16, transposed per 32-key chunk: dst[chunk][d=64][kr=32].
// ---------------------------------------------------------------------------
__global__ __launch_bounds__(256) void trans_v0(const float* __restrict__ v0,
                                                short* __restrict__ v0t) {
    __shared__ float tile[32][65];
    const size_t base = (size_t)blockIdx.x * 2048;
    const int t = threadIdx.x;
#pragma unroll
    for (int i = 0; i < 2; ++i) {
        int f = t + i * 256;                 // float4 unit, 512 total
        int kr = f >> 4, d4 = (f & 15) * 4;
        float4 v = *(const float4*)&v0[base + kr * 64 + d4];
        tile[kr][d4 + 0] = v.x; tile[kr][d4 + 1] = v.y;
        tile[kr][d4 + 2] = v.z; tile[kr][d4 + 3] = v.w;
    }
    __syncthreads();
#pragma unroll
    for (int i = 0; i < 2; ++i) {
        int g = t + i * 256;                 // s16x4 unit in dst, 512 total
        int d = g >> 3, kr4 = (g & 7) * 4;
        s16x4 o = {f2bf(tile[kr4 + 0][d]), f2bf(tile[kr4 + 1][d]),
                   f2bf(tile[kr4 + 2][d]), f2bf(tile[kr4 + 3][d])};
        *(s16x4*)&v0t[base + d * 32 + kr4] = o;
    }
}

// ---------------------------------------------------------------------------
__global__ __launch_bounds__(256) void cast_w_t(const float* __restrict__ Wq,
                                                const float* __restrict__ Wk,
                                                const float* __restrict__ Wv,
                                                short* __restrict__ WtAll) {
    const float* W = (blockIdx.z == 0) ? Wq : (blockIdx.z == 1) ? Wk : Wv;
    short* Wt = WtAll + (size_t)blockIdx.z * HIDDEN * HIDDEN;
    __shared__ __align__(16) float tile[32][33];
    const int kb0 = blockIdx.y * 32, nb0 = blockIdx.x * 32;
    const int r = threadIdx.x >> 3, c4 = (threadIdx.x & 7) * 4;
    float4 v = *(const float4*)&W[(size_t)(kb0 + r) * HIDDEN + nb0 + c4];
    tile[r][c4 + 0] = v.x; tile[r][c4 + 1] = v.y;
    tile[r][c4 + 2] = v.z; tile[r][c4 + 3] = v.w;
    __syncthreads();
    s16x4 o = {f2bf(tile[c4 + 0][r]), f2bf(tile[c4 + 1][r]),
               f2bf(tile[c4 + 2][r]), f2bf(tile[c4 + 3][r])};
    *(s16x4*)&Wt[(size_t)(nb0 + r) * HIDDEN + kb0 + c4] = o;
}

// ---------------------------------------------------------------------------
// QKV GEMM: 128x128 tile, BK=64, global_load_lds(16B) staging, XOR-swizzled
// unpadded LDS (col8 ^= row&7). 4 waves, each 64x64 via 4x4 of 16x16x32 mfma.
// ---------------------------------------------------------------------------
__global__ __launch_bounds__(256) void qkv_mfma(
    const short* __restrict__ hsb, const short* __restrict__ WtAll,
    const float* __restrict__ bq, const float* __restrict__ bk,
    const float* __restrict__ bv,
    short* __restrict__ qo, short* __restrict__ ko, short* __restrict__ vo)
{
    const int z = blockIdx.z;
    const short* Wt = WtAll + (size_t)z * HIDDEN * HIDDEN;
    const float* bias = (z == 0) ? bq : (z == 1) ? bk : bv;
    short* outp = (z == 0) ? qo : (z == 1) ? ko : vo;

    __shared__ __align__(16) short smem[128 * 128];   // As(16KB) | Bs(16KB); epilogue reuses all
    short* As = smem;
    short* Bs = smem + 128 * 64;

    const int t = threadIdx.x;
    const int lane = t & 63, w = t >> 6;
    const int l15 = lane & 15, quad = lane >> 4;
    const int mBase = blockIdx.y * 128, nBase = blockIdx.x * 128;
    const int mw = (w & 1) * 64, nw = (w >> 1) * 64;

    // staging geometry: per gll16, 64 lanes cover 8 rows x 64 shorts (1 KB)
    const int srow_in = lane >> 3;                    // 0..7 within the 8-row group
    const int scol8 = (lane & 7) ^ srow_in;           // XOR swizzle (row&7 == srow_in)

    f32x4 acc[4][4];
    const f32x4 z4 = {0.f, 0.f, 0.f, 0.f};
#pragma unroll
    for (int i = 0; i < 4; ++i)
#pragma unroll
        for (int j = 0; j < 4; ++j) acc[i][j] = z4;

    for (int kb = 0; kb < HIDDEN; kb += 64) {
        __syncthreads();                              // prev tile's frag reads done
#pragma unroll
        for (int j = 0; j < 4; ++j) {
            int row = w * 32 + j * 8 + srow_in;       // 0..127
            gll16(&hsb[(size_t)(mBase + row) * HIDDEN + kb + scol8 * 8],
                  &As[(w * 32 + j * 8) * 64]);
            gll16(&Wt[(size_t)(nBase + row) * HIDDEN + kb + scol8 * 8],
                  &Bs[(w * 32 + j * 8) * 64]);
        }
        __syncthreads();                              // drains vmcnt for the DMA
#pragma unroll
        for (int kc = 0; kc < 2; ++kc) {
            s16x8 a[4], b[4];
#pragma unroll
            for (int mt = 0; mt < 4; ++mt) {
                int row = mw + mt * 16 + l15;
                int c8 = (kc * 4 + quad) ^ (row & 7);
                a[mt] = *(const s16x8*)&As[row * 64 + c8 * 8];
            }
#pragma unroll
            for (int nt = 0; nt < 4; ++nt) {
                int row = nw + nt * 16 + l15;
                int c8 = (kc * 4 + quad) ^ (row & 7);
                b[nt] = *(const s16x8*)&Bs[row * 64 + c8 * 8];
            }
#pragma unroll
            for (int mt = 0; mt < 4; ++mt)
#pragma unroll
                for (int nt = 0; nt < 4; ++nt)
                    acc[mt][nt] = __builtin_amdgcn_mfma_f32_16x16x32_bf16(
                        a[mt], b[nt], acc[mt][nt], 0, 0, 0);
        }
    }

    // epilogue: bias, bf16, LDS transpose, head-split coalesced store
    __syncthreads();
#pragma unroll
    for (int nt = 0; nt < 4; ++nt) {
        float bvv = bias[nBase + nw + nt * 16 + l15];
        int col = nw + nt * 16 + l15;
#pragma unroll
        for (int mt = 0; mt < 4; ++mt)
#pragma unroll
            for (int r = 0; r < 4; ++r) {
                int row = mw + mt * 16 + quad * 4 + r;
                smem[row * 128 + col] = f2bf(acc[mt][nt][r] + bvv);
            }
    }
    __syncthreads();
#pragma unroll
    for (int i = 0; i < 8; ++i) {
        int f = t + i * 256;
        int row = f >> 4, c8 = (f & 15) * 8;
        uint4 val = *(const uint4*)&smem[row * 128 + c8];
        int m = mBase + row, n = nBase + c8;
        size_t dst = (((size_t)(m >> 5) * NUM_HEADS + (n >> 6)) * SLOT_LEN + (m & 31)) * 64 + (n & 63);
        *(uint4*)&outp[dst] = val;
    }
}

// ---------------------------------------------------------------------------
// Attention: one WAVE per (B,h); 21 chunks of 32 keys.
// launch_bounds(256,3): LDS caps us at 3 blocks/CU (12 waves) anyway, so let
// the allocator keep ~170 VGPRs -> prefetch buffers stay live & independent
// (at 124 VGPR the allocator serialized the prefetch into vmcnt chains).
// Chunks 0-15 (cache0): bf16 pre-converted K/V, K prefetch 2-deep, V 1-deep.
// Chunks 16-19 (cache1): f32 path, K 1-deep prefetch.
// Chunk 20 (self): bf16 from qkv workspace.
// ---------------------------------------------------------------------------
__global__ __launch_bounds__(256, 3) void attn_mfma(
    const short* __restrict__ qb, const short* __restrict__ kbuf,
    const short* __restrict__ vbuf,
    const short* __restrict__ k0c, const short* __restrict__ v0t,
    const float* __restrict__ c1k, const float* __restrict__ c1v,
    const float* __restrict__ mask, float* __restrict__ out)
{
    __shared__ __align__(16) short Klds[4][32][72];
    __shared__ __align__(16) short Vt[4][64][40];
    __shared__ __align__(16) short Plds[4][32][36];

    const int t = threadIdx.x, lane = t & 63, w = t >> 6;
    const int task = blockIdx.x * 4 + w;      // < 2880
    const int B = task / 12, h = task % 12;
    const int l15 = lane & 15, quad = lane >> 4;

    const short* qp  = qb  + (size_t)(B * NUM_HEADS + h) * SLOT_LEN * 64;
    const short* ksp = kbuf + (size_t)(B * NUM_HEADS + h) * SLOT_LEN * 64;
    const short* vsp = vbuf + (size_t)(B * NUM_HEADS + h) * SLOT_LEN * 64;
    const short* k0p = k0c + (size_t)((B & 7) * NUM_HEADS + h) * LEN0 * 64;
    const short* v0p = v0t + (size_t)((B & 7) * NUM_HEADS + h) * LEN0 * 64;
    const float* k1p = c1k + (size_t)(B * NUM_HEADS + h) * LEN1 * 64;
    const float* v1p = c1v + (size_t)(B * NUM_HEADS + h) * LEN1 * 64;
    const float* mp  = mask + (size_t)B * KTOT;

    short (*K)[72] = Klds[w];
    short (*V)[40] = Vt[w];
    short (*P)[36] = Plds[w];

    const int skey = lane >> 4;               // f32 staging: lane -> (key%4, c4)
    const int sc4 = (lane & 15) << 2;

    // bf16 staging geometry (chunks 0-15)
    const int kkey = lane >> 3, ku = lane & 7;     // K: [i*8+kkey][ku*8]
    const int vd = lane >> 2, vu = lane & 3;       // V: [i*16+vd][vu*8]

    // Q fragments
    s16x8 qf[2][2];
#pragma unroll
    for (int qh = 0; qh < 2; ++qh)
#pragma unroll
        for (int kc = 0; kc < 2; ++kc)
            qf[qh][kc] = *(const s16x8*)&qp[(qh * 16 + l15) * 64 + kc * 32 + quad * 8];

    const f32x4 z4 = {0.f, 0.f, 0.f, 0.f};
    f32x4 o[2][4];
    float lpart[2][4];
#pragma unroll
    for (int qh = 0; qh < 2; ++qh) {
#pragma unroll
        for (int dq = 0; dq < 4; ++dq) o[qh][dq] = z4;
#pragma unroll
        for (int r = 0; r < 4; ++r) lpart[qh][r] = 0.f;
    }

    s16x8 kpre[2][4];                         // 2-deep bf16 K prefetch (chunks 0-15)
    s16x8 vpre[4];                            // 1-deep bf16 V prefetch
    float4 kreg[8];                           // f32 K prefetch (chunks 16-19)
    float mreg0, mreg1;

    const float LOG2E = 1.4426950408889634f;
    const float SCL   = 0.125f * 1.4426950408889634f;

    auto issue_k0 = [&](int c, int slot) {    // c in [0,16)
        const short* kcb = k0p + c * 2048;
#pragma unroll
        for (int i = 0; i < 4; ++i)
            kpre[slot][i] = *(const s16x8*)&kcb[(i * 64 + lane) * 8];
    };
    auto issue_v0 = [&](int c) {              // c in [0,16)
        const short* vcb = v0p + c * 2048;
#pragma unroll
        for (int i = 0; i < 4; ++i)
            vpre[i] = *(const s16x8*)&vcb[(i * 64 + lane) * 8];
    };
    auto issue_k1 = [&](int c) {              // c in [16,20): cache1 f32 K
        const float* sk = k1p + (c - 16) * 2048;
#pragma unroll
        for (int i = 0; i < 8; ++i)
            kreg[i] = *(const float4*)&sk[(i * 4 + skey) * 64 + sc4];
    };
    auto issue_mask = [&](int c) {            // pre-scaled by log2(e) for exp2
        mreg0 = mp[c * 32 + l15] * LOG2E;
        mreg1 = mp[c * 32 + 16 + l15] * LOG2E;
    };

    issue_k0(0, 0);
    issue_k0(1, 1);
    issue_v0(0);
    issue_mask(0);

    for (int c = 0; c < 21; ++c) {
        const float mv0 = mreg0, mv1 = mreg1;
        float4 vv[8];
        bool f32path = (c >= 16 && c < 20);

        if (c < 16) {
            // ---- K: prefetched bf16 regs -> LDS (waits its own vmcnt slice)
#pragma unroll
            for (int i = 0; i < 4; ++i)
                *(s16x8*)&K[i * 8 + kkey][ku * 8] = kpre[c & 1][i];
            // ---- reissue K prefetch 2 chunks ahead into the freed slot
            if (c + 2 < 16) issue_k0(c + 2, c & 1);
            // ---- V: prefetched bf16 regs -> LDS
#pragma unroll
            for (int i = 0; i < 4; ++i)
                *(s16x8*)&V[i * 16 + vd][vu * 8] = vpre[i];
            if (c + 1 < 16) issue_v0(c + 1);
            if (c == 15) issue_k1(16);        // transition into f32 K path
        } else if (c < 20) {
            // ---- cache1: f32 K (prefetched) -> convert -> LDS
#pragma unroll
            for (int i = 0; i < 8; ++i) {
                s16x4 kk = {f2bf(kreg[i].x), f2bf(kreg[i].y), f2bf(kreg[i].z), f2bf(kreg[i].w)};
                *(s16x4*)&K[i * 4 + skey][sc4] = kk;
            }
            // ---- cache1 V loads for current chunk (consumed after QK+exp)
            const float* sv = v1p + (c - 16) * 2048;
#pragma unroll
            for (int i = 0; i < 8; ++i)
                vv[i] = *(const float4*)&sv[(i * 4 + skey) * 64 + sc4];
            if (c + 1 < 20) issue_k1(c + 1);
        } else {  // self chunk: bf16 from workspace, synchronous
#pragma unroll
            for (int i = 0; i < 8; ++i) {
                int key = i * 4 + skey;
                *(s16x4*)&K[key][sc4] = *(const s16x4*)&ksp[key * 64 + sc4];
            }
            short vtmp[32];
#pragma unroll
            for (int key = 0; key < 32; ++key) vtmp[key] = vsp[key * 64 + lane];
#pragma unroll
            for (int k4 = 0; k4 < 8; ++k4) {
                s16x4 vo4 = {vtmp[k4 * 4 + 0], vtmp[k4 * 4 + 1],
                             vtmp[k4 * 4 + 2], vtmp[k4 * 4 + 3]};
                *(s16x4*)&V[lane][k4 * 4] = vo4;
            }
        }

        if (c + 1 < 21) issue_mask(c + 1);

        // ---- scores S = Q K^T
        f32x4 s[2][2];
#pragma unroll
        for (int qh = 0; qh < 2; ++qh)
#pragma unroll
            for (int kh = 0; kh < 2; ++kh) s[qh][kh] = z4;
#pragma unroll
        for (int kh = 0; kh < 2; ++kh) {
            s16x8 kf0 = *(const s16x8*)&K[kh * 16 + l15][quad * 8];
            s16x8 kf1 = *(const s16x8*)&K[kh * 16 + l15][32 + quad * 8];
#pragma unroll
            for (int qh = 0; qh < 2; ++qh) {
                s[qh][kh] = __builtin_amdgcn_mfma_f32_16x16x32_bf16(qf[qh][0], kf0, s[qh][kh], 0, 0, 0);
                s[qh][kh] = __builtin_amdgcn_mfma_f32_16x16x32_bf16(qf[qh][1], kf1, s[qh][kh], 0, 0, 0);
            }
        }

        // ---- exp2 (log2e pre-folded), accumulate l, write P
#pragma unroll
        for (int qh = 0; qh < 2; ++qh)
#pragma unroll
            for (int kh = 0; kh < 2; ++kh) {
                float mv = kh ? mv1 : mv0;
#pragma unroll
                for (int r = 0; r < 4; ++r) {
                    float p = exp2f(fmaf(s[qh][kh][r], SCL, mv));
                    lpart[qh][r] += p;
                    P[qh * 16 + quad * 4 + r][kh * 16 + l15] = f2bf(p);
                }
            }

        // ---- cache1 V: registers -> transposed LDS (loads hidden behind QK+exp)
        if (f32path) {
#pragma unroll
            for (int i = 0; i < 8; ++i) {
                int key = i * 4 + skey;
                V[sc4 + 0][key] = f2bf(vv[i].x);
                V[sc4 + 1][key] = f2bf(vv[i].y);
                V[sc4 + 2][key] = f2bf(vv[i].z);
                V[sc4 + 3][key] = f2bf(vv[i].w);
            }
        }

        // ---- O += P V
#pragma unroll
        for (int qh = 0; qh < 2; ++qh) {
            s16x4 plo = *(const s16x4*)&P[qh * 16 + l15][quad * 8];
            s16x4 phi = *(const s16x4*)&P[qh * 16 + l15][quad * 8 + 4];
            s16x8 pf = __builtin_shufflevector(plo, phi, 0, 1, 2, 3, 4, 5, 6, 7);
#pragma unroll
            for (int dq = 0; dq < 4; ++dq) {
                s16x8 vf = *(const s16x8*)&V[dq * 16 + l15][quad * 8];
                o[qh][dq] = __builtin_amdgcn_mfma_f32_16x16x32_bf16(pf, vf, o[qh][dq], 0, 0, 0);
            }
        }
    }

    // ---- final reduce + store
    float linv[2][4];
#pragma unroll
    for (int qh = 0; qh < 2; ++qh)
#pragma unroll
        for (int r = 0; r < 4; ++r) {
            float l = lpart[qh][r];
            l += __shfl_xor(l, 1);
            l += __shfl_xor(l, 2);
            l += __shfl_xor(l, 4);
            l += __shfl_xor(l, 8);
            linv[qh][r] = 1.f / l;
        }

#pragma unroll
    for (int qh = 0; qh < 2; ++qh)
#pragma unroll
        for (int dq = 0; dq < 4; ++dq)
#pragma unroll
            for (int r = 0; r < 4; ++r) {
                int row = qh * 16 + quad * 4 + r;
                out[((size_t)B * SLOT_LEN + row) * HIDDEN + h * 64 + dq * 16 + l15] =
                    o[qh][dq][r] * linv[qh][r];
            }
}

// ---------------------------------------------------------------------------
extern "C" void kernel_launch(void* const* d_in, const int* in_sizes, int n_in,
                              void* d_out, int out_size, void* d_ws, size_t ws_size,
                              hipStream_t stream) {
    const float* hs   = (const float*)d_in[0];
    const float* mask = (const float*)d_in[1];
    const float* c0k  = (const float*)d_in[2];
    const float* c0v  = (const float*)d_in[3];
    const float* c1k  = (const float*)d_in[4];
    const float* c1v  = (const float*)d_in[5];
    const float* Wq   = (const float*)d_in[6];
    const float* bq   = (const float*)d_in[7];
    const float* Wk   = (const float*)d_in[8];
    const float* bk   = (const float*)d_in[9];
    const float* Wv   = (const float*)d_in[10];
    const float* bv   = (const float*)d_in[11];
    float* out = (float*)d_out;

    short* hsb = (short*)d_ws;
    short* WtA = hsb + (size_t)M_TOK * HIDDEN;
    short* qb  = WtA + (size_t)3 * HIDDEN * HIDDEN;
    short* kbw = qb + (size_t)M_TOK * HIDDEN;
    short* vbw = kbw + (size_t)M_TOK * HIDDEN;
    // cache0 bf16 pre-pass buffers: reuse hsb+WtA region (dead after qkv_mfma).
    short* k0c = (short*)d_ws;
    short* v0t = k0c + (size_t)BS * NUM_HEADS * LEN0 * HEAD_DIM;

    cast_hs<<<(M_TOK * HIDDEN / 4 + 255) / 256, 256, 0, stream>>>(hs, hsb, M_TOK * HIDDEN / 4);
    cast_w_t<<<dim3(24, 24, 3), 256, 0, stream>>>(Wq, Wk, Wv, WtA);
    qkv_mfma<<<dim3(HIDDEN / 128, M_TOK / 128, 3), 256, 0, stream>>>(
        hsb, WtA, bq, bk, bv, qb, kbw, vbw);
    // pre-pass AFTER qkv (workspace reuse): flat-cast K0, chunk-transpose V0
    {
        int n4 = BS * NUM_HEADS * LEN0 * HEAD_DIM / 4;   // 786432
        cast_hs<<<(n4 + 255) / 256, 256, 0, stream>>>(c0k, k0c, n4);
        trans_v0<<<BS * NUM_HEADS * (LEN0 / 32), 256, 0, stream>>>(c0v, v0t);
    }
    attn_mfma<<<720, 256, 0, stream>>>(qb, kbw, vbw, k0c, v0t, c1k, c1v, mask, out);
}

// Round 4
// 407.814 us; speedup vs baseline: 4.0425x; 4.0425x over previous
//
#include <hip/hip_runtime.h>
#include <math.h>

#define NUM_HEADS 12
#define HEAD_DIM  64
#define HIDDEN    768
#define BS        8
#define FULL      240
#define SLOT_LEN  32
#define LEN0      512
#define LEN1      128
#define KTOT      672
#define M_TOK     (FULL * SLOT_LEN)   // 7680

typedef float f32x4 __attribute__((ext_vector_type(4)));
typedef short s16x8 __attribute__((ext_vector_type(8)));
typedef short s16x4 __attribute__((ext_vector_type(4)));

__device__ __forceinline__ short f2bf(float x) {
    unsigned u = __float_as_uint(x);
    unsigned r = (u + 0x7fffu + ((u >> 16) & 1u)) >> 16;
    return (short)r;
}

// async global->LDS, 16B per lane; lds base must be wave-uniform
__device__ __forceinline__ void gll16(const short* g, short* l) {
    __builtin_amdgcn_global_load_lds(
        (const __attribute__((address_space(1))) unsigned int*)g,
        (__attribute__((address_space(3))) unsigned int*)l, 16, 0, 0);
}

// ---------------------------------------------------------------------------
__global__ __launch_bounds__(256) void cast_hs(const float* __restrict__ in,
                                               short* __restrict__ out, int n4) {
    int i = blockIdx.x * 256 + threadIdx.x;
    if (i < n4) {
        float4 v = ((const float4*)in)[i];
        s16x4 o = {f2bf(v.x), f2bf(v.y), f2bf(v.z), f2bf(v.w)};
        ((s16x4*)out)[i] = o;
    }
}

// ---------------------------------------------------------------------------
// cache0_key -> bf16 per 32-key chunk, XOR-swizzled: logical (row,col8,sub)
// stored at row*64 + (col8 ^ (row&7))*8 + sub. One block per chunk.
// ---------------------------------------------------------------------------
__global__ __launch_bounds__(256) void cast_k0(const float* __restrict__ k0,
                                               short* __restrict__ k0c) {
    const size_t base = (size_t)blockIdx.x * 2048;
    const int t = threadIdx.x;
    const int row = t >> 3, c8 = t & 7;
    const float* src = &k0[base + row * 64 + c8 * 8];
    float4 a = *(const float4*)src;
    float4 b = *(const float4*)(src + 4);
    s16x8 o = {f2bf(a.x), f2bf(a.y), f2bf(a.z), f2bf(a.w),
               f2bf(b.x), f2bf(b.y), f2bf(b.z), f2bf(b.w)};
    *(s16x8*)&k0c[base + row * 64 + (size_t)((c8 ^ (row & 7)) * 8)] = o;
}

// ---------------------------------------------------------------------------
// cache0_value -> bf16, transposed per 32-key chunk, XOR-swizzled:
// logical (d, key) stored at d*32 + ((key>>3) ^ ((d>>1)&3))*8 + (key&7).
// ---------------------------------------------------------------------------
__global__ __launch_bounds__(256) void trans_v0(const float* __restrict__ v0,
                                                short* __restrict__ v0t) {
    __shared__ float tile[32][65];
    const size_t base = (size_t)blockIdx.x * 2048;
    const int t = threadIdx.x;
#pragma unroll
    for (int i = 0; i < 2; ++i) {
        int f = t + i * 256;                 // float4 unit, 512 total
        int kr = f >> 4, d4 = (f & 15) * 4;
        float4 v = *(const float4*)&v0[base + kr * 64 + d4];
        tile[kr][d4 + 0] = v.x; tile[kr][d4 + 1] = v.y;
        tile[kr][d4 + 2] = v.z; tile[kr][d4 + 3] = v.w;
    }
    __syncthreads();
#pragma unroll
    for (int i = 0; i < 2; ++i) {
        int g = t + i * 256;                 // s16x4 unit in dst, 512 total
        int d = g >> 3, kr4 = (g & 7) * 4;   // keys kr4..kr4+3
        s16x4 o = {f2bf(tile[kr4 + 0][d]), f2bf(tile[kr4 + 1][d]),
                   f2bf(tile[kr4 + 2][d]), f2bf(tile[kr4 + 3][d])};
        int grp = (kr4 >> 3) ^ ((d >> 1) & 3);
        *(s16x4*)&v0t[base + d * 32 + grp * 8 + (kr4 & 7)] = o;
    }
}

// ---------------------------------------------------------------------------
__global__ __launch_bounds__(256) void cast_w_t(const float* __restrict__ Wq,
                                                const float* __restrict__ Wk,
                                                const float* __restrict__ Wv,
                                                short* __restrict__ WtAll) {
    const float* W = (blockIdx.z == 0) ? Wq : (blockIdx.z == 1) ? Wk : Wv;
    short* Wt = WtAll + (size_t)blockIdx.z * HIDDEN * HIDDEN;
    __shared__ __align__(16) float tile[32][33];
    const int kb0 = blockIdx.y * 32, nb0 = blockIdx.x * 32;
    const int r = threadIdx.x >> 3, c4 = (threadIdx.x & 7) * 4;
    float4 v = *(const float4*)&W[(size_t)(kb0 + r) * HIDDEN + nb0 + c4];
    tile[r][c4 + 0] = v.x; tile[r][c4 + 1] = v.y;
    tile[r][c4 + 2] = v.z; tile[r][c4 + 3] = v.w;
    __syncthreads();
    s16x4 o = {f2bf(tile[c4 + 0][r]), f2bf(tile[c4 + 1][r]),
               f2bf(tile[c4 + 2][r]), f2bf(tile[c4 + 3][r])};
    *(s16x4*)&Wt[(size_t)(nb0 + r) * HIDDEN + kb0 + c4] = o;
}

// ---------------------------------------------------------------------------
// QKV GEMM: 128x128 tile, BK=64, global_load_lds(16B) staging, XOR-swizzled
// unpadded LDS (col8 ^= row&7). 4 waves, each 64x64 via 4x4 of 16x16x32 mfma.
// ---------------------------------------------------------------------------
__global__ __launch_bounds__(256) void qkv_mfma(
    const short* __restrict__ hsb, const short* __restrict__ WtAll,
    const float* __restrict__ bq, const float* __restrict__ bk,
    const float* __restrict__ bv,
    short* __restrict__ qo, short* __restrict__ ko, short* __restrict__ vo)
{
    const int z = blockIdx.z;
    const short* Wt = WtAll + (size_t)z * HIDDEN * HIDDEN;
    const float* bias = (z == 0) ? bq : (z == 1) ? bk : bv;
    short* outp = (z == 0) ? qo : (z == 1) ? ko : vo;

    __shared__ __align__(16) short smem[128 * 128];   // As(16KB) | Bs(16KB); epilogue reuses all
    short* As = smem;
    short* Bs = smem + 128 * 64;

    const int t = threadIdx.x;
    const int lane = t & 63, w = t >> 6;
    const int l15 = lane & 15, quad = lane >> 4;
    const int mBase = blockIdx.y * 128, nBase = blockIdx.x * 128;
    const int mw = (w & 1) * 64, nw = (w >> 1) * 64;

    // staging geometry: per gll16, 64 lanes cover 8 rows x 64 shorts (1 KB)
    const int srow_in = lane >> 3;                    // 0..7 within the 8-row group
    const int scol8 = (lane & 7) ^ srow_in;           // XOR swizzle (row&7 == srow_in)

    f32x4 acc[4][4];
    const f32x4 z4 = {0.f, 0.f, 0.f, 0.f};
#pragma unroll
    for (int i = 0; i < 4; ++i)
#pragma unroll
        for (int j = 0; j < 4; ++j) acc[i][j] = z4;

    for (int kb = 0; kb < HIDDEN; kb += 64) {
        __syncthreads();                              // prev tile's frag reads done
#pragma unroll
        for (int j = 0; j < 4; ++j) {
            int row = w * 32 + j * 8 + srow_in;       // 0..127
            gll16(&hsb[(size_t)(mBase + row) * HIDDEN + kb + scol8 * 8],
                  &As[(w * 32 + j * 8) * 64]);
            gll16(&Wt[(size_t)(nBase + row) * HIDDEN + kb + scol8 * 8],
                  &Bs[(w * 32 + j * 8) * 64]);
        }
        __syncthreads();                              // drains vmcnt for the DMA
#pragma unroll
        for (int kc = 0; kc < 2; ++kc) {
            s16x8 a[4], b[4];
#pragma unroll
            for (int mt = 0; mt < 4; ++mt) {
                int row = mw + mt * 16 + l15;
                int c8 = (kc * 4 + quad) ^ (row & 7);
                a[mt] = *(const s16x8*)&As[row * 64 + c8 * 8];
            }
#pragma unroll
            for (int nt = 0; nt < 4; ++nt) {
                int row = nw + nt * 16 + l15;
                int c8 = (kc * 4 + quad) ^ (row & 7);
                b[nt] = *(const s16x8*)&Bs[row * 64 + c8 * 8];
            }
#pragma unroll
            for (int mt = 0; mt < 4; ++mt)
#pragma unroll
                for (int nt = 0; nt < 4; ++nt)
                    acc[mt][nt] = __builtin_amdgcn_mfma_f32_16x16x32_bf16(
                        a[mt], b[nt], acc[mt][nt], 0, 0, 0);
        }
    }

    // epilogue: bias, bf16, LDS transpose, head-split coalesced store
    __syncthreads();
#pragma unroll
    for (int nt = 0; nt < 4; ++nt) {
        float bvv = bias[nBase + nw + nt * 16 + l15];
        int col = nw + nt * 16 + l15;
#pragma unroll
        for (int mt = 0; mt < 4; ++mt)
#pragma unroll
            for (int r = 0; r < 4; ++r) {
                int row = mw + mt * 16 + quad * 4 + r;
                smem[row * 128 + col] = f2bf(acc[mt][nt][r] + bvv);
            }
    }
    __syncthreads();
#pragma unroll
    for (int i = 0; i < 8; ++i) {
        int f = t + i * 256;
        int row = f >> 4, c8 = (f & 15) * 8;
        uint4 val = *(const uint4*)&smem[row * 128 + c8];
        int m = mBase + row, n = nBase + c8;
        size_t dst = (((size_t)(m >> 5) * NUM_HEADS + (n >> 6)) * SLOT_LEN + (m & 31)) * 64 + (n & 63);
        *(uint4*)&outp[dst] = val;
    }
}

// ---------------------------------------------------------------------------
// Attention: one WAVE per (B,h); 21 chunks of 32 keys.
// Unpadded XOR-swizzled LDS: K[32][64] (col8^=row&7), V[64][32] and P[32][32]
// (grp^=(row>>1)&3). Per-wave LDS = 10 KB -> block 40960 B -> 4 blocks/CU
// (16 waves/CU, was 12). cache0 chunks stage pre-swizzled bf16 linearly.
// Plain launch_bounds: the (256,3) variant made hipcc clamp to 84 VGPR and
// spill 326 MB to scratch (13x regression) — never use the 2nd arg here.
// ---------------------------------------------------------------------------
__global__ __launch_bounds__(256) void attn_mfma(
    const short* __restrict__ qb, const short* __restrict__ kbuf,
    const short* __restrict__ vbuf,
    const short* __restrict__ k0c, const short* __restrict__ v0t,
    const float* __restrict__ c1k, const float* __restrict__ c1v,
    const float* __restrict__ mask, float* __restrict__ out)
{
    __shared__ __align__(16) short Klds[4][32][64];
    __shared__ __align__(16) short Vt[4][64][32];
    __shared__ __align__(16) short Plds[4][32][32];

    const int t = threadIdx.x, lane = t & 63, w = t >> 6;
    const int task = blockIdx.x * 4 + w;      // < 2880
    const int B = task / 12, h = task % 12;
    const int l15 = lane & 15, quad = lane >> 4;

    const short* qp  = qb  + (size_t)(B * NUM_HEADS + h) * SLOT_LEN * 64;
    const short* ksp = kbuf + (size_t)(B * NUM_HEADS + h) * SLOT_LEN * 64;
    const short* vsp = vbuf + (size_t)(B * NUM_HEADS + h) * SLOT_LEN * 64;
    const short* k0p = k0c + (size_t)((B & 7) * NUM_HEADS + h) * LEN0 * 64;
    const short* v0p = v0t + (size_t)((B & 7) * NUM_HEADS + h) * LEN0 * 64;
    const float* k1p = c1k + (size_t)(B * NUM_HEADS + h) * LEN1 * 64;
    const float* v1p = c1v + (size_t)(B * NUM_HEADS + h) * LEN1 * 64;
    const float* mp  = mask + (size_t)B * KTOT;

    short (*K)[64] = Klds[w];
    short (*V)[32] = Vt[w];
    short (*P)[32] = Plds[w];
    short* Kf = &K[0][0];
    short* Vf = &V[0][0];

    const int skey = lane >> 4;               // f32 staging: lane -> (key%4, c4)
    const int sc4 = (lane & 15) << 2;

    // Q fragments
    s16x8 qf[2][2];
#pragma unroll
    for (int qh = 0; qh < 2; ++qh)
#pragma unroll
        for (int kc = 0; kc < 2; ++kc)
            qf[qh][kc] = *(const s16x8*)&qp[(qh * 16 + l15) * 64 + kc * 32 + quad * 8];

    const f32x4 z4 = {0.f, 0.f, 0.f, 0.f};
    f32x4 o[2][4];
    float lpart[2][4];
#pragma unroll
    for (int qh = 0; qh < 2; ++qh) {
#pragma unroll
        for (int dq = 0; dq < 4; ++dq) o[qh][dq] = z4;
#pragma unroll
        for (int r = 0; r < 4; ++r) lpart[qh][r] = 0.f;
    }

    s16x8 kpre[4], vpre[4];                   // bf16 prefetch (chunks 0-15)
    float4 kreg[8];                           // f32 K prefetch (chunks 16-19)
    float mreg0, mreg1;

    const float LOG2E = 1.4426950408889634f;
    const float SCL   = 0.125f * 1.4426950408889634f;

    auto issue_bf = [&](int c) {              // c in [0,16): pre-swizzled linear
        const short* kcb = k0p + c * 2048;
        const short* vcb = v0p + c * 2048;
#pragma unroll
        for (int i = 0; i < 4; ++i) {
            kpre[i] = *(const s16x8*)&kcb[(i * 64 + lane) * 8];
            vpre[i] = *(const s16x8*)&vcb[(i * 64 + lane) * 8];
        }
    };
    auto issue_k1 = [&](int c) {              // c in [16,20): cache1 f32 K
        const float* sk = k1p + (c - 16) * 2048;
#pragma unroll
        for (int i = 0; i < 8; ++i)
            kreg[i] = *(const float4*)&sk[(i * 4 + skey) * 64 + sc4];
    };
    auto issue_mask = [&](int c) {            // pre-scaled by log2(e) for exp2
        mreg0 = mp[c * 32 + l15] * LOG2E;
        mreg1 = mp[c * 32 + 16 + l15] * LOG2E;
    };

    issue_bf(0);
    issue_mask(0);

    for (int c = 0; c < 21; ++c) {
        const float mv0 = mreg0, mv1 = mreg1;
        float4 vv[8];
        bool f32path = (c >= 16 && c < 20);

        if (c < 16) {
            // ---- staged bf16 K,V -> LDS, linear (swizzle baked into memory)
#pragma unroll
            for (int i = 0; i < 4; ++i)
                *(s16x8*)&Kf[(i * 64 + lane) * 8] = kpre[i];
#pragma unroll
            for (int i = 0; i < 4; ++i)
                *(s16x8*)&Vf[(i * 64 + lane) * 8] = vpre[i];
            if (c + 1 < 16) issue_bf(c + 1);
            if (c == 15) issue_k1(16);        // transition into f32 K path
        } else if (c < 20) {
            // ---- cache1: f32 K (prefetched) -> convert -> swizzled LDS
#pragma unroll
            for (int i = 0; i < 8; ++i) {
                s16x4 kk = {f2bf(kreg[i].x), f2bf(kreg[i].y), f2bf(kreg[i].z), f2bf(kreg[i].w)};
                int row = i * 4 + skey;
                *(s16x4*)&K[row][((l15 >> 1) ^ (row & 7)) * 8 + (l15 & 1) * 4] = kk;
            }
            // ---- cache1 V loads for current chunk (consumed after QK+exp)
            const float* sv = v1p + (c - 16) * 2048;
#pragma unroll
            for (int i = 0; i < 8; ++i)
                vv[i] = *(const float4*)&sv[(i * 4 + skey) * 64 + sc4];
            if (c + 1 < 20) issue_k1(c + 1);
        } else {  // self chunk: bf16 from workspace, synchronous
#pragma unroll
            for (int i = 0; i < 8; ++i) {
                int key = i * 4 + skey;
                *(s16x4*)&K[key][((l15 >> 1) ^ (key & 7)) * 8 + (l15 & 1) * 4] =
                    *(const s16x4*)&ksp[key * 64 + sc4];
            }
            short vtmp[32];
#pragma unroll
            for (int key = 0; key < 32; ++key) vtmp[key] = vsp[key * 64 + lane];
#pragma unroll
            for (int k4 = 0; k4 < 8; ++k4) {
                s16x4 vo4 = {vtmp[k4 * 4 + 0], vtmp[k4 * 4 + 1],
                             vtmp[k4 * 4 + 2], vtmp[k4 * 4 + 3]};
                int grp = (k4 >> 1) ^ ((lane >> 1) & 3);
                *(s16x4*)&V[lane][grp * 8 + (k4 & 1) * 4] = vo4;
            }
        }

        if (c + 1 < 21) issue_mask(c + 1);

        // ---- scores S = Q K^T (K read with XOR de-swizzle)
        f32x4 s[2][2];
#pragma unroll
        for (int qh = 0; qh < 2; ++qh)
#pragma unroll
            for (int kh = 0; kh < 2; ++kh) s[qh][kh] = z4;
#pragma unroll
        for (int kh = 0; kh < 2; ++kh) {
            int rowk = kh * 16 + l15;
            s16x8 kf0 = *(const s16x8*)&K[rowk][(quad ^ (rowk & 7)) * 8];
            s16x8 kf1 = *(const s16x8*)&K[rowk][((4 + quad) ^ (rowk & 7)) * 8];
#pragma unroll
            for (int qh = 0; qh < 2; ++qh) {
                s[qh][kh] = __builtin_amdgcn_mfma_f32_16x16x32_bf16(qf[qh][0], kf0, s[qh][kh], 0, 0, 0);
                s[qh][kh] = __builtin_amdgcn_mfma_f32_16x16x32_bf16(qf[qh][1], kf1, s[qh][kh], 0, 0, 0);
            }
        }

        // ---- exp2 (log2e pre-folded), accumulate l, write P (swizzled)
#pragma unroll
        for (int qh = 0; qh < 2; ++qh)
#pragma unroll
            for (int kh = 0; kh < 2; ++kh) {
                float mv = kh ? mv1 : mv0;
#pragma unroll
                for (int r = 0; r < 4; ++r) {
                    float p = exp2f(fmaf(s[qh][kh][r], SCL, mv));
                    lpart[qh][r] += p;
                    int prow = qh * 16 + quad * 4 + r;
                    int pswz = ((kh * 2 + (l15 >> 3)) ^ ((prow >> 1) & 3)) * 8 + (l15 & 7);
                    P[prow][pswz] = f2bf(p);
                }
            }

        // ---- cache1 V: registers -> transposed swizzled LDS
        if (f32path) {
#pragma unroll
            for (int i = 0; i < 8; ++i) {
                int key = i * 4 + skey;
                int kg = key >> 3, ks = key & 7;
#pragma unroll
                for (int j = 0; j < 4; ++j) {
                    int rowv = sc4 + j;
                    float fv = (j == 0) ? vv[i].x : (j == 1) ? vv[i].y : (j == 2) ? vv[i].z : vv[i].w;
                    V[rowv][(kg ^ ((rowv >> 1) & 3)) * 8 + ks] = f2bf(fv);
                }
            }
        }

        // ---- O += P V (both read with XOR de-swizzle)
#pragma unroll
        for (int qh = 0; qh < 2; ++qh) {
            int prow2 = qh * 16 + l15;
            int pg = (quad ^ ((l15 >> 1) & 3)) * 8;
            s16x4 plo = *(const s16x4*)&P[prow2][pg];
            s16x4 phi = *(const s16x4*)&P[prow2][pg + 4];
            s16x8 pf = __builtin_shufflevector(plo, phi, 0, 1, 2, 3, 4, 5, 6, 7);
#pragma unroll
            for (int dq = 0; dq < 4; ++dq) {
                int vrow = dq * 16 + l15;
                s16x8 vf = *(const s16x8*)&V[vrow][(quad ^ ((l15 >> 1) & 3)) * 8];
                o[qh][dq] = __builtin_amdgcn_mfma_f32_16x16x32_bf16(pf, vf, o[qh][dq], 0, 0, 0);
            }
        }
    }

    // ---- final reduce + store
    float linv[2][4];
#pragma unroll
    for (int qh = 0; qh < 2; ++qh)
#pragma unroll
        for (int r = 0; r < 4; ++r) {
            float l = lpart[qh][r];
            l += __shfl_xor(l, 1);
            l += __shfl_xor(l, 2);
            l += __shfl_xor(l, 4);
            l += __shfl_xor(l, 8);
            linv[qh][r] = 1.f / l;
        }

#pragma unroll
    for (int qh = 0; qh < 2; ++qh)
#pragma unroll
        for (int dq = 0; dq < 4; ++dq)
#pragma unroll
            for (int r = 0; r < 4; ++r) {
                int row = qh * 16 + quad * 4 + r;
                out[((size_t)B * SLOT_LEN + row) * HIDDEN + h * 64 + dq * 16 + l15] =
                    o[qh][dq][r] * linv[qh][r];
            }
}

// ---------------------------------------------------------------------------
extern "C" void kernel_launch(void* const* d_in, const int* in_sizes, int n_in,
                              void* d_out, int out_size, void* d_ws, size_t ws_size,
                              hipStream_t stream) {
    const float* hs   = (const float*)d_in[0];
    const float* mask = (const float*)d_in[1];
    const float* c0k  = (const float*)d_in[2];
    const float* c0v  = (const float*)d_in[3];
    const float* c1k  = (const float*)d_in[4];
    const float* c1v  = (const float*)d_in[5];
    const float* Wq   = (const float*)d_in[6];
    const float* bq   = (const float*)d_in[7];
    const float* Wk   = (const float*)d_in[8];
    const float* bk   = (const float*)d_in[9];
    const float* Wv   = (const float*)d_in[10];
    const float* bv   = (const float*)d_in[11];
    float* out = (float*)d_out;

    short* hsb = (short*)d_ws;
    short* WtA = hsb + (size_t)M_TOK * HIDDEN;
    short* qb  = WtA + (size_t)3 * HIDDEN * HIDDEN;
    short* kbw = qb + (size_t)M_TOK * HIDDEN;
    short* vbw = kbw + (size_t)M_TOK * HIDDEN;
    // cache0 bf16 pre-pass buffers: reuse hsb+WtA region (dead after qkv_mfma).
    short* k0c = (short*)d_ws;
    short* v0t = k0c + (size_t)BS * NUM_HEADS * LEN0 * HEAD_DIM;

    cast_hs<<<(M_TOK * HIDDEN / 4 + 255) / 256, 256, 0, stream>>>(hs, hsb, M_TOK * HIDDEN / 4);
    cast_w_t<<<dim3(24, 24, 3), 256, 0, stream>>>(Wq, Wk, Wv, WtA);
    qkv_mfma<<<dim3(HIDDEN / 128, M_TOK / 128, 3), 256, 0, stream>>>(
        hsb, WtA, bq, bk, bv, qb, kbw, vbw);
    // pre-pass AFTER qkv (workspace reuse): swizzle-cast K0, transpose+swizzle V0
    cast_k0<<<BS * NUM_HEADS * (LEN0 / 32), 256, 0, stream>>>(c0k, k0c);
    trans_v0<<<BS * NUM_HEADS * (LEN0 / 32), 256, 0, stream>>>(c0v, v0t);
    attn_mfma<<<720, 256, 0, stream>>>(qb, kbw, vbw, k0c, v0t, c1k, c1v, mask, out);
}

// Round 5
// 369.310 us; speedup vs baseline: 4.4640x; 1.1043x over previous
//
#include <hip/hip_runtime.h>
#include <math.h>

#define NUM_HEADS 12
#define HEAD_DIM  64
#define HIDDEN    768
#define BS        8
#define FULL      240
#define SLOT_LEN  32
#define LEN0      512
#define LEN1      128
#define KTOT      672
#define M_TOK     (FULL * SLOT_LEN)   // 7680

typedef float f32x4 __attribute__((ext_vector_type(4)));
typedef short s16x8 __attribute__((ext_vector_type(8)));
typedef short s16x4 __attribute__((ext_vector_type(4)));

__device__ __forceinline__ short f2bf(float x) {
    unsigned u = __float_as_uint(x);
    unsigned r = (u + 0x7fffu + ((u >> 16) & 1u)) >> 16;
    return (short)r;
}

// async global->LDS, 16B per lane; lds base must be wave-uniform
__device__ __forceinline__ void gll16(const short* g, short* l) {
    __builtin_amdgcn_global_load_lds(
        (const __attribute__((address_space(1))) unsigned int*)g,
        (__attribute__((address_space(3))) unsigned int*)l, 16, 0, 0);
}

// ---------------------------------------------------------------------------
__global__ __launch_bounds__(256) void cast_hs(const float* __restrict__ in,
                                               short* __restrict__ out, int n4) {
    int i = blockIdx.x * 256 + threadIdx.x;
    if (i < n4) {
        float4 v = ((const float4*)in)[i];
        s16x4 o = {f2bf(v.x), f2bf(v.y), f2bf(v.z), f2bf(v.w)};
        ((s16x4*)out)[i] = o;
    }
}

// ---------------------------------------------------------------------------
// Fused cache0 pre-pass (one launch, grid.y selects path):
//  y==0: K -> bf16, XOR-swizzled per 32-key chunk (row*64 + (c8^(row&7))*8)
//  y==1: V -> bf16, transposed per chunk, swizzled (d*32 + ((key>>3)^((d>>1)&3))*8 + key&7)
// ---------------------------------------------------------------------------
__global__ __launch_bounds__(256) void prep_c0(const float* __restrict__ k0,
                                               const float* __restrict__ v0,
                                               short* __restrict__ k0c,
                                               short* __restrict__ v0t) {
    __shared__ float tile[32][65];
    const size_t base = (size_t)blockIdx.x * 2048;
    const int t = threadIdx.x;
    if (blockIdx.y == 0) {
        const int row = t >> 3, c8 = t & 7;
        const float* src = &k0[base + row * 64 + c8 * 8];
        float4 a = *(const float4*)src;
        float4 b = *(const float4*)(src + 4);
        s16x8 o = {f2bf(a.x), f2bf(a.y), f2bf(a.z), f2bf(a.w),
                   f2bf(b.x), f2bf(b.y), f2bf(b.z), f2bf(b.w)};
        *(s16x8*)&k0c[base + row * 64 + (size_t)((c8 ^ (row & 7)) * 8)] = o;
    } else {
#pragma unroll
        for (int i = 0; i < 2; ++i) {
            int f = t + i * 256;
            int kr = f >> 4, d4 = (f & 15) * 4;
            float4 v = *(const float4*)&v0[base + kr * 64 + d4];
            tile[kr][d4 + 0] = v.x; tile[kr][d4 + 1] = v.y;
            tile[kr][d4 + 2] = v.z; tile[kr][d4 + 3] = v.w;
        }
        __syncthreads();
#pragma unroll
        for (int i = 0; i < 2; ++i) {
            int g = t + i * 256;
            int d = g >> 3, kr4 = (g & 7) * 4;
            s16x4 o = {f2bf(tile[kr4 + 0][d]), f2bf(tile[kr4 + 1][d]),
                       f2bf(tile[kr4 + 2][d]), f2bf(tile[kr4 + 3][d])};
            int grp = (kr4 >> 3) ^ ((d >> 1) & 3);
            *(s16x4*)&v0t[base + d * 32 + grp * 8 + (kr4 & 7)] = o;
        }
    }
}

// ---------------------------------------------------------------------------
__global__ __launch_bounds__(256) void cast_w_t(const float* __restrict__ Wq,
                                                const float* __restrict__ Wk,
                                                const float* __restrict__ Wv,
                                                short* __restrict__ WtAll) {
    const float* W = (blockIdx.z == 0) ? Wq : (blockIdx.z == 1) ? Wk : Wv;
    short* Wt = WtAll + (size_t)blockIdx.z * HIDDEN * HIDDEN;
    __shared__ __align__(16) float tile[32][33];
    const int kb0 = blockIdx.y * 32, nb0 = blockIdx.x * 32;
    const int r = threadIdx.x >> 3, c4 = (threadIdx.x & 7) * 4;
    float4 v = *(const float4*)&W[(size_t)(kb0 + r) * HIDDEN + nb0 + c4];
    tile[r][c4 + 0] = v.x; tile[r][c4 + 1] = v.y;
    tile[r][c4 + 2] = v.z; tile[r][c4 + 3] = v.w;
    __syncthreads();
    s16x4 o = {f2bf(tile[c4 + 0][r]), f2bf(tile[c4 + 1][r]),
               f2bf(tile[c4 + 2][r]), f2bf(tile[c4 + 3][r])};
    *(s16x4*)&Wt[(size_t)(nb0 + r) * HIDDEN + kb0 + c4] = o;
}

// ---------------------------------------------------------------------------
// QKV GEMM: 128x128 tile, BK=64, global_load_lds(16B) staging, XOR-swizzled
// unpadded LDS (col8 ^= row&7). 4 waves, each 64x64 via 4x4 of 16x16x32 mfma.
// ---------------------------------------------------------------------------
__global__ __launch_bounds__(256) void qkv_mfma(
    const short* __restrict__ hsb, const short* __restrict__ WtAll,
    const float* __restrict__ bq, const float* __restrict__ bk,
    const float* __restrict__ bv,
    short* __restrict__ qo, short* __restrict__ ko, short* __restrict__ vo)
{
    const int z = blockIdx.z;
    const short* Wt = WtAll + (size_t)z * HIDDEN * HIDDEN;
    const float* bias = (z == 0) ? bq : (z == 1) ? bk : bv;
    short* outp = (z == 0) ? qo : (z == 1) ? ko : vo;

    __shared__ __align__(16) short smem[128 * 128];
    short* As = smem;
    short* Bs = smem + 128 * 64;

    const int t = threadIdx.x;
    const int lane = t & 63, w = t >> 6;
    const int l15 = lane & 15, quad = lane >> 4;
    const int mBase = blockIdx.y * 128, nBase = blockIdx.x * 128;
    const int mw = (w & 1) * 64, nw = (w >> 1) * 64;

    const int srow_in = lane >> 3;
    const int scol8 = (lane & 7) ^ srow_in;

    f32x4 acc[4][4];
    const f32x4 z4 = {0.f, 0.f, 0.f, 0.f};
#pragma unroll
    for (int i = 0; i < 4; ++i)
#pragma unroll
        for (int j = 0; j < 4; ++j) acc[i][j] = z4;

    for (int kb = 0; kb < HIDDEN; kb += 64) {
        __syncthreads();
#pragma unroll
        for (int j = 0; j < 4; ++j) {
            int row = w * 32 + j * 8 + srow_in;
            gll16(&hsb[(size_t)(mBase + row) * HIDDEN + kb + scol8 * 8],
                  &As[(w * 32 + j * 8) * 64]);
            gll16(&Wt[(size_t)(nBase + row) * HIDDEN + kb + scol8 * 8],
                  &Bs[(w * 32 + j * 8) * 64]);
        }
        __syncthreads();
#pragma unroll
        for (int kc = 0; kc < 2; ++kc) {
            s16x8 a[4], b[4];
#pragma unroll
            for (int mt = 0; mt < 4; ++mt) {
                int row = mw + mt * 16 + l15;
                int c8 = (kc * 4 + quad) ^ (row & 7);
                a[mt] = *(const s16x8*)&As[row * 64 + c8 * 8];
            }
#pragma unroll
            for (int nt = 0; nt < 4; ++nt) {
                int row = nw + nt * 16 + l15;
                int c8 = (kc * 4 + quad) ^ (row & 7);
                b[nt] = *(const s16x8*)&Bs[row * 64 + c8 * 8];
            }
#pragma unroll
            for (int mt = 0; mt < 4; ++mt)
#pragma unroll
                for (int nt = 0; nt < 4; ++nt)
                    acc[mt][nt] = __builtin_amdgcn_mfma_f32_16x16x32_bf16(
                        a[mt], b[nt], acc[mt][nt], 0, 0, 0);
        }
    }

    __syncthreads();
#pragma unroll
    for (int nt = 0; nt < 4; ++nt) {
        float bvv = bias[nBase + nw + nt * 16 + l15];
        int col = nw + nt * 16 + l15;
#pragma unroll
        for (int mt = 0; mt < 4; ++mt)
#pragma unroll
            for (int r = 0; r < 4; ++r) {
                int row = mw + mt * 16 + quad * 4 + r;
                smem[row * 128 + col] = f2bf(acc[mt][nt][r] + bvv);
            }
    }
    __syncthreads();
#pragma unroll
    for (int i = 0; i < 8; ++i) {
        int f = t + i * 256;
        int row = f >> 4, c8 = (f & 15) * 8;
        uint4 val = *(const uint4*)&smem[row * 128 + c8];
        int m = mBase + row, n = nBase + c8;
        size_t dst = (((size_t)(m >> 5) * NUM_HEADS + (n >> 6)) * SLOT_LEN + (m & 31)) * 64 + (n & 63);
        *(uint4*)&outp[dst] = val;
    }
}

// ---------------------------------------------------------------------------
// Attention v3: ONE BLOCK per (B,h) task (grid 2880). The 4 waves split the
// 21 KV chunks (no online max -> partial o/l sum trivially); block-level
// merge via LDS at the end. Per-wave private K[32][64]/V[64][32]/P[32][32],
// XOR-swizzled, 10KB/wave -> LDS 40960 (4 blocks/CU). No barriers in main
// loop. f32 cache1 path: ONE chunk/wave, half-sized reg buffers (kr[4]/vv[4]
// reused for both halves) to keep VGPR <= 128 (152 VGPR halved occupancy in
// R4: waves/SIMD steps at 128).
// Chunk map: wave w: cache0 {4w..4w+3} + cache1 {16+w}; wave3 also self(20).
// ---------------------------------------------------------------------------
__global__ __launch_bounds__(256) void attn_mfma(
    const short* __restrict__ qb, const short* __restrict__ kbuf,
    const short* __restrict__ vbuf,
    const short* __restrict__ k0c, const short* __restrict__ v0t,
    const float* __restrict__ c1k, const float* __restrict__ c1v,
    const float* __restrict__ mask, float* __restrict__ out)
{
    __shared__ __align__(16) short sm_s[20480];   // 40 KB: 4 x (K|V|P) / merge scratch

    const int t = threadIdx.x, lane = t & 63, w = t >> 6;
    const int task = blockIdx.x;                  // < 2880
    const int B = task / 12, h = task % 12;
    const int l15 = lane & 15, quad = lane >> 4;

    const short* qp  = qb  + (size_t)(B * NUM_HEADS + h) * SLOT_LEN * 64;
    const short* ksp = kbuf + (size_t)(B * NUM_HEADS + h) * SLOT_LEN * 64;
    const short* vsp = vbuf + (size_t)(B * NUM_HEADS + h) * SLOT_LEN * 64;
    const short* k0p = k0c + (size_t)((B & 7) * NUM_HEADS + h) * LEN0 * 64;
    const short* v0p = v0t + (size_t)((B & 7) * NUM_HEADS + h) * LEN0 * 64;
    const float* k1p = c1k + (size_t)(B * NUM_HEADS + h) * LEN1 * 64;
    const float* v1p = c1v + (size_t)(B * NUM_HEADS + h) * LEN1 * 64;
    const float* mp  = mask + (size_t)B * KTOT;

    short (*K)[64] = (short(*)[64])(sm_s + w * 5120);
    short (*V)[32] = (short(*)[32])(sm_s + w * 5120 + 2048);
    short (*P)[32] = (short(*)[32])(sm_s + w * 5120 + 4096);
    short* Kf = sm_s + w * 5120;
    short* Vf = sm_s + w * 5120 + 2048;

    const int skey = lane >> 4;               // f32 staging: lane -> (key%4, c4)
    const int sc4 = (lane & 15) << 2;

    const float LOG2E = 1.4426950408889634f;
    const float SCL   = 0.125f * 1.4426950408889634f;

    // Q fragments
    s16x8 qf[2][2];
#pragma unroll
    for (int qh = 0; qh < 2; ++qh)
#pragma unroll
        for (int kc = 0; kc < 2; ++kc)
            qf[qh][kc] = *(const s16x8*)&qp[(qh * 16 + l15) * 64 + kc * 32 + quad * 8];

    const f32x4 z4 = {0.f, 0.f, 0.f, 0.f};
    f32x4 o[2][4];
    float lpart[2][4];
#pragma unroll
    for (int qh = 0; qh < 2; ++qh) {
#pragma unroll
        for (int dq = 0; dq < 4; ++dq) o[qh][dq] = z4;
#pragma unroll
        for (int r = 0; r < 4; ++r) lpart[qh][r] = 0.f;
    }

    // ---- shared compute pieces --------------------------------------------
    auto qk_exp = [&](float mv0, float mv1) {
        f32x4 s[2][2];
#pragma unroll
        for (int qh = 0; qh < 2; ++qh)
#pragma unroll
            for (int kh = 0; kh < 2; ++kh) s[qh][kh] = z4;
#pragma unroll
        for (int kh = 0; kh < 2; ++kh) {
            int rowk = kh * 16 + l15;
            s16x8 kf0 = *(const s16x8*)&K[rowk][(quad ^ (rowk & 7)) * 8];
            s16x8 kf1 = *(const s16x8*)&K[rowk][((4 + quad) ^ (rowk & 7)) * 8];
#pragma unroll
            for (int qh = 0; qh < 2; ++qh) {
                s[qh][kh] = __builtin_amdgcn_mfma_f32_16x16x32_bf16(qf[qh][0], kf0, s[qh][kh], 0, 0, 0);
                s[qh][kh] = __builtin_amdgcn_mfma_f32_16x16x32_bf16(qf[qh][1], kf1, s[qh][kh], 0, 0, 0);
            }
        }
#pragma unroll
        for (int qh = 0; qh < 2; ++qh)
#pragma unroll
            for (int kh = 0; kh < 2; ++kh) {
                float mv = kh ? mv1 : mv0;
#pragma unroll
                for (int r = 0; r < 4; ++r) {
                    float p = exp2f(fmaf(s[qh][kh][r], SCL, mv));
                    lpart[qh][r] += p;
                    int prow = qh * 16 + quad * 4 + r;
                    int pswz = ((kh * 2 + (l15 >> 3)) ^ ((prow >> 1) & 3)) * 8 + (l15 & 7);
                    P[prow][pswz] = f2bf(p);
                }
            }
    };
    auto pv = [&]() {
#pragma unroll
        for (int qh = 0; qh < 2; ++qh) {
            int prow2 = qh * 16 + l15;
            int pg = (quad ^ ((l15 >> 1) & 3)) * 8;
            s16x4 plo = *(const s16x4*)&P[prow2][pg];
            s16x4 phi = *(const s16x4*)&P[prow2][pg + 4];
            s16x8 pf = __builtin_shufflevector(plo, phi, 0, 1, 2, 3, 4, 5, 6, 7);
#pragma unroll
            for (int dq = 0; dq < 4; ++dq) {
                int vrow = dq * 16 + l15;
                s16x8 vf = *(const s16x8*)&V[vrow][(quad ^ ((l15 >> 1) & 3)) * 8];
                o[qh][dq] = __builtin_amdgcn_mfma_f32_16x16x32_bf16(pf, vf, o[qh][dq], 0, 0, 0);
            }
        }
    };

    // ---- phase A: self chunk (wave 3 only, c = 20) ------------------------
    if (w == 3) {
#pragma unroll
        for (int i = 0; i < 8; ++i) {
            int key = i * 4 + skey;
            *(s16x4*)&K[key][((l15 >> 1) ^ (key & 7)) * 8 + (l15 & 1) * 4] =
                *(const s16x4*)&ksp[key * 64 + sc4];
        }
        short vtmp[32];
#pragma unroll
        for (int key = 0; key < 32; ++key) vtmp[key] = vsp[key * 64 + lane];
#pragma unroll
        for (int k4 = 0; k4 < 8; ++k4) {
            s16x4 vo4 = {vtmp[k4 * 4 + 0], vtmp[k4 * 4 + 1],
                         vtmp[k4 * 4 + 2], vtmp[k4 * 4 + 3]};
            int grp = (k4 >> 1) ^ ((lane >> 1) & 3);
            *(s16x4*)&V[lane][grp * 8 + (k4 & 1) * 4] = vo4;
        }
        float mv0 = mp[20 * 32 + l15] * LOG2E;
        float mv1 = mp[20 * 32 + 16 + l15] * LOG2E;
        qk_exp(mv0, mv1);
        pv();
    }

    // ---- phase B: one cache1 chunk (c = 16+w), register-diet f32 path -----
    {
        int c = 16 + w;
        const float* sk = k1p + (c - 16) * 2048;
        const float* sv = v1p + (c - 16) * 2048;
        float4 kr[4], vv[4];
#pragma unroll
        for (int i = 0; i < 4; ++i)
            kr[i] = *(const float4*)&sk[(i * 4 + skey) * 64 + sc4];
#pragma unroll
        for (int i = 0; i < 4; ++i)
            vv[i] = *(const float4*)&sv[(i * 4 + skey) * 64 + sc4];
#pragma unroll
        for (int i = 0; i < 4; ++i) {          // keys 0..15
            s16x4 kk = {f2bf(kr[i].x), f2bf(kr[i].y), f2bf(kr[i].z), f2bf(kr[i].w)};
            int row = i * 4 + skey;
            *(s16x4*)&K[row][((l15 >> 1) ^ (row & 7)) * 8 + (l15 & 1) * 4] = kk;
        }
#pragma unroll
        for (int i = 0; i < 4; ++i)            // reuse kr: keys 16..31
            kr[i] = *(const float4*)&sk[((i + 4) * 4 + skey) * 64 + sc4];
#pragma unroll
        for (int i = 0; i < 4; ++i) {
            s16x4 kk = {f2bf(kr[i].x), f2bf(kr[i].y), f2bf(kr[i].z), f2bf(kr[i].w)};
            int row = (i + 4) * 4 + skey;
            *(s16x4*)&K[row][((l15 >> 1) ^ (row & 7)) * 8 + (l15 & 1) * 4] = kk;
        }
        float mv0 = mp[c * 32 + l15] * LOG2E;
        float mv1 = mp[c * 32 + 16 + l15] * LOG2E;
        qk_exp(mv0, mv1);                      // vvA latency hidden here
#pragma unroll
        for (int i = 0; i < 4; ++i) {          // scatter vvA: keys 0..15
            int key = i * 4 + skey;
            int kg = key >> 3, ks = key & 7;
#pragma unroll
            for (int j = 0; j < 4; ++j) {
                int rowv = sc4 + j;
                float fv = (j == 0) ? vv[i].x : (j == 1) ? vv[i].y : (j == 2) ? vv[i].z : vv[i].w;
                V[rowv][(kg ^ ((rowv >> 1) & 3)) * 8 + ks] = f2bf(fv);
            }
        }
#pragma unroll
        for (int i = 0; i < 4; ++i)            // reuse vv: keys 16..31
            vv[i] = *(const float4*)&sv[((i + 4) * 4 + skey) * 64 + sc4];
#pragma unroll
        for (int i = 0; i < 4; ++i) {
            int key = (i + 4) * 4 + skey;
            int kg = key >> 3, ks = key & 7;
#pragma unroll
            for (int j = 0; j < 4; ++j) {
                int rowv = sc4 + j;
                float fv = (j == 0) ? vv[i].x : (j == 1) ? vv[i].y : (j == 2) ? vv[i].z : vv[i].w;
                V[rowv][(kg ^ ((rowv >> 1) & 3)) * 8 + ks] = f2bf(fv);
            }
        }
        pv();
    }

    // ---- phase C: 4 cache0 chunks {4w..4w+3}, bf16 staged, 1-deep prefetch
    {
        s16x8 kpre[4], vpre[4];
        const int cbase = w * 4;
        auto issue_bf = [&](int c) {
            const short* kcb = k0p + c * 2048;
            const short* vcb = v0p + c * 2048;
#pragma unroll
            for (int i = 0; i < 4; ++i) {
                kpre[i] = *(const s16x8*)&kcb[(i * 64 + lane) * 8];
                vpre[i] = *(const s16x8*)&vcb[(i * 64 + lane) * 8];
            }
        };
        issue_bf(cbase);
#pragma unroll
        for (int j = 0; j < 4; ++j) {
            int c = cbase + j;
#pragma unroll
            for (int i = 0; i < 4; ++i)
                *(s16x8*)&Kf[(i * 64 + lane) * 8] = kpre[i];
#pragma unroll
            for (int i = 0; i < 4; ++i)
                *(s16x8*)&Vf[(i * 64 + lane) * 8] = vpre[i];
            if (j + 1 < 4) issue_bf(c + 1);
            float mv0 = mp[c * 32 + l15] * LOG2E;
            float mv1 = mp[c * 32 + 16 + l15] * LOG2E;
            qk_exp(mv0, mv1);
            pv();
        }
    }

    // ---- merge: sum 4 wave-partials (o, l) via LDS scratch ----------------
    float lred[2][4];
#pragma unroll
    for (int qh = 0; qh < 2; ++qh)
#pragma unroll
        for (int r = 0; r < 4; ++r) {
            float l = lpart[qh][r];
            l += __shfl_xor(l, 1);
            l += __shfl_xor(l, 2);
            l += __shfl_xor(l, 4);
            l += __shfl_xor(l, 8);
            lred[qh][r] = l;
        }

    __syncthreads();                           // everyone done with K/V/P
    float* smf = (float*)sm_s;                 // osum[4][32][64] | lsum[4][32]
#pragma unroll
    for (int qh = 0; qh < 2; ++qh)
#pragma unroll
        for (int dq = 0; dq < 4; ++dq)
#pragma unroll
            for (int r = 0; r < 4; ++r) {
                int row = qh * 16 + quad * 4 + r, col = dq * 16 + l15;
                smf[w * 2048 + row * 64 + col] = o[qh][dq][r];
            }
    if (l15 == 0) {
#pragma unroll
        for (int qh = 0; qh < 2; ++qh)
#pragma unroll
            for (int r = 0; r < 4; ++r)
                smf[8192 + w * 32 + qh * 16 + quad * 4 + r] = lred[qh][r];
    }
    __syncthreads();

    {
        int row = t >> 3, c8 = (t & 7) * 8;
        float lt = smf[8192 + row] + smf[8192 + 32 + row] +
                   smf[8192 + 64 + row] + smf[8192 + 96 + row];
        float inv = 1.f / lt;
        float4 o0, o1;
#pragma unroll
        for (int j = 0; j < 4; ++j) {
            int col = c8 + j;
            o0[j] = (smf[row * 64 + col] + smf[2048 + row * 64 + col] +
                     smf[4096 + row * 64 + col] + smf[6144 + row * 64 + col]) * inv;
        }
#pragma unroll
        for (int j = 0; j < 4; ++j) {
            int col = c8 + 4 + j;
            o1[j] = (smf[row * 64 + col] + smf[2048 + row * 64 + col] +
                     smf[4096 + row * 64 + col] + smf[6144 + row * 64 + col]) * inv;
        }
        float* op = &out[((size_t)B * SLOT_LEN + row) * HIDDEN + h * 64 + c8];
        *(float4*)op = o0;
        *(float4*)(op + 4) = o1;
    }
}

// ---------------------------------------------------------------------------
extern "C" void kernel_launch(void* const* d_in, const int* in_sizes, int n_in,
                              void* d_out, int out_size, void* d_ws, size_t ws_size,
                              hipStream_t stream) {
    const float* hs   = (const float*)d_in[0];
    const float* mask = (const float*)d_in[1];
    const float* c0k  = (const float*)d_in[2];
    const float* c0v  = (const float*)d_in[3];
    const float* c1k  = (const float*)d_in[4];
    const float* c1v  = (const float*)d_in[5];
    const float* Wq   = (const float*)d_in[6];
    const float* bq   = (const float*)d_in[7];
    const float* Wk   = (const float*)d_in[8];
    const float* bk   = (const float*)d_in[9];
    const float* Wv   = (const float*)d_in[10];
    const float* bv   = (const float*)d_in[11];
    float* out = (float*)d_out;

    short* hsb = (short*)d_ws;
    short* WtA = hsb + (size_t)M_TOK * HIDDEN;
    short* qb  = WtA + (size_t)3 * HIDDEN * HIDDEN;
    short* kbw = qb + (size_t)M_TOK * HIDDEN;
    short* vbw = kbw + (size_t)M_TOK * HIDDEN;
    // cache0 bf16 pre-pass buffers: reuse hsb+WtA region (dead after qkv_mfma).
    short* k0c = (short*)d_ws;
    short* v0t = k0c + (size_t)BS * NUM_HEADS * LEN0 * HEAD_DIM;

    cast_hs<<<(M_TOK * HIDDEN / 4 + 255) / 256, 256, 0, stream>>>(hs, hsb, M_TOK * HIDDEN / 4);
    cast_w_t<<<dim3(24, 24, 3), 256, 0, stream>>>(Wq, Wk, Wv, WtA);
    qkv_mfma<<<dim3(HIDDEN / 128, M_TOK / 128, 3), 256, 0, stream>>>(
        hsb, WtA, bq, bk, bv, qb, kbw, vbw);
    // pre-pass AFTER qkv (workspace reuse): swizzle-cast K0 + transpose V0, fused
    prep_c0<<<dim3(BS * NUM_HEADS * (LEN0 / 32), 2), 256, 0, stream>>>(c0k, c0v, k0c, v0t);
    attn_mfma<<<FULL * NUM_HEADS, 256, 0, stream>>>(qb, kbw, vbw, k0c, v0t, c1k, c1v, mask, out);
}

// Round 6
// 359.831 us; speedup vs baseline: 4.5816x; 1.0263x over previous
//
#include <hip/hip_runtime.h>
#include <math.h>

#define NUM_HEADS 12
#define HEAD_DIM  64
#define HIDDEN    768
#define BS        8
#define FULL      240
#define SLOT_LEN  32
#define LEN0      512
#define LEN1      128
#define KTOT      672
#define M_TOK     (FULL * SLOT_LEN)   // 7680

typedef float f32x4 __attribute__((ext_vector_type(4)));
typedef short s16x8 __attribute__((ext_vector_type(8)));
typedef short s16x4 __attribute__((ext_vector_type(4)));

__device__ __forceinline__ short f2bf(float x) {
    unsigned u = __float_as_uint(x);
    unsigned r = (u + 0x7fffu + ((u >> 16) & 1u)) >> 16;
    return (short)r;
}

// async global->LDS, 16B per lane; lds base must be wave-uniform
__device__ __forceinline__ void gll16(const short* g, short* l) {
    __builtin_amdgcn_global_load_lds(
        (const __attribute__((address_space(1))) unsigned int*)g,
        (__attribute__((address_space(3))) unsigned int*)l, 16, 0, 0);
}

// ---------------------------------------------------------------------------
__global__ __launch_bounds__(256) void cast_hs(const float* __restrict__ in,
                                               short* __restrict__ out, int n4) {
    int i = blockIdx.x * 256 + threadIdx.x;
    if (i < n4) {
        float4 v = ((const float4*)in)[i];
        s16x4 o = {f2bf(v.x), f2bf(v.y), f2bf(v.z), f2bf(v.w)};
        ((s16x4*)out)[i] = o;
    }
}

// ---------------------------------------------------------------------------
// cache0_value -> bf16 frag-major per 32-key chunk (2048 shorts/chunk):
// v0f[chunk*2048 + (dq*64 + quad*16 + l15)*8 + j] = V[key=quad*8+j][d=dq*16+l15]
// This is exactly the PV MFMA B-fragment, so attention loads it as 16B/lane.
// ---------------------------------------------------------------------------
__global__ __launch_bounds__(256) void prep_v0(const float* __restrict__ v0,
                                               short* __restrict__ v0f) {
    __shared__ float tile[32][65];
    const size_t base = (size_t)blockIdx.x * 2048;
    const int t = threadIdx.x;
#pragma unroll
    for (int i = 0; i < 2; ++i) {
        int f = t + i * 256;                 // float4 unit, 512 total
        int kr = f >> 4, d4 = (f & 15) * 4;
        float4 v = *(const float4*)&v0[base + kr * 64 + d4];
        tile[kr][d4 + 0] = v.x; tile[kr][d4 + 1] = v.y;
        tile[kr][d4 + 2] = v.z; tile[kr][d4 + 3] = v.w;
    }
    __syncthreads();
    const int dq = t >> 6, lane = t & 63;
    const int quad = lane >> 4, l15 = lane & 15;
    s16x8 o = {f2bf(tile[quad * 8 + 0][dq * 16 + l15]),
               f2bf(tile[quad * 8 + 1][dq * 16 + l15]),
               f2bf(tile[quad * 8 + 2][dq * 16 + l15]),
               f2bf(tile[quad * 8 + 3][dq * 16 + l15]),
               f2bf(tile[quad * 8 + 4][dq * 16 + l15]),
               f2bf(tile[quad * 8 + 5][dq * 16 + l15]),
               f2bf(tile[quad * 8 + 6][dq * 16 + l15]),
               f2bf(tile[quad * 8 + 7][dq * 16 + l15])};
    *(s16x8*)&v0f[base + (size_t)t * 8] = o;
}

// ---------------------------------------------------------------------------
__global__ __launch_bounds__(256) void cast_w_t(const float* __restrict__ Wq,
                                                const float* __restrict__ Wk,
                                                const float* __restrict__ Wv,
                                                short* __restrict__ WtAll) {
    const float* W = (blockIdx.z == 0) ? Wq : (blockIdx.z == 1) ? Wk : Wv;
    short* Wt = WtAll + (size_t)blockIdx.z * HIDDEN * HIDDEN;
    __shared__ __align__(16) float tile[32][33];
    const int kb0 = blockIdx.y * 32, nb0 = blockIdx.x * 32;
    const int r = threadIdx.x >> 3, c4 = (threadIdx.x & 7) * 4;
    float4 v = *(const float4*)&W[(size_t)(kb0 + r) * HIDDEN + nb0 + c4];
    tile[r][c4 + 0] = v.x; tile[r][c4 + 1] = v.y;
    tile[r][c4 + 2] = v.z; tile[r][c4 + 3] = v.w;
    __syncthreads();
    s16x4 o = {f2bf(tile[c4 + 0][r]), f2bf(tile[c4 + 1][r]),
               f2bf(tile[c4 + 2][r]), f2bf(tile[c4 + 3][r])};
    *(s16x4*)&Wt[(size_t)(nb0 + r) * HIDDEN + kb0 + c4] = o;
}

// ---------------------------------------------------------------------------
// QKV GEMM: 128x128 tile, BK=64, global_load_lds(16B) staging, XOR-swizzled
// unpadded LDS. Epilogue: z==0 (Q) and z==1 (K) write row-major [B,h][key][d];
// z==2 (V) writes FRAG-MAJOR per (B,h): (dq*64+quad*16+l15)*8+j = V[q*8+j][..]
// via a transposed smem pass (stride 144: 16B-aligned cols, 4-way banks).
// ---------------------------------------------------------------------------
__global__ __launch_bounds__(256) void qkv_mfma(
    const short* __restrict__ hsb, const short* __restrict__ WtAll,
    const float* __restrict__ bq, const float* __restrict__ bk,
    const float* __restrict__ bv,
    short* __restrict__ qo, short* __restrict__ ko, short* __restrict__ vo)
{
    const int z = blockIdx.z;
    const short* Wt = WtAll + (size_t)z * HIDDEN * HIDDEN;
    const float* bias = (z == 0) ? bq : (z == 1) ? bk : bv;
    short* outp = (z == 0) ? qo : (z == 1) ? ko : vo;

    __shared__ __align__(16) short smem[128 * 144];   // 36.9KB; K-loop uses first 32KB
    short* As = smem;
    short* Bs = smem + 128 * 64;

    const int t = threadIdx.x;
    const int lane = t & 63, w = t >> 6;
    const int l15 = lane & 15, quad = lane >> 4;
    const int mBase = blockIdx.y * 128, nBase = blockIdx.x * 128;
    const int mw = (w & 1) * 64, nw = (w >> 1) * 64;

    const int srow_in = lane >> 3;
    const int scol8 = (lane & 7) ^ srow_in;

    f32x4 acc[4][4];
    const f32x4 z4 = {0.f, 0.f, 0.f, 0.f};
#pragma unroll
    for (int i = 0; i < 4; ++i)
#pragma unroll
        for (int j = 0; j < 4; ++j) acc[i][j] = z4;

    for (int kb = 0; kb < HIDDEN; kb += 64) {
        __syncthreads();
#pragma unroll
        for (int j = 0; j < 4; ++j) {
            int row = w * 32 + j * 8 + srow_in;
            gll16(&hsb[(size_t)(mBase + row) * HIDDEN + kb + scol8 * 8],
                  &As[(w * 32 + j * 8) * 64]);
            gll16(&Wt[(size_t)(nBase + row) * HIDDEN + kb + scol8 * 8],
                  &Bs[(w * 32 + j * 8) * 64]);
        }
        __syncthreads();
#pragma unroll
        for (int kc = 0; kc < 2; ++kc) {
            s16x8 a[4], b[4];
#pragma unroll
            for (int mt = 0; mt < 4; ++mt) {
                int row = mw + mt * 16 + l15;
                int c8 = (kc * 4 + quad) ^ (row & 7);
                a[mt] = *(const s16x8*)&As[row * 64 + c8 * 8];
            }
#pragma unroll
            for (int nt = 0; nt < 4; ++nt) {
                int row = nw + nt * 16 + l15;
                int c8 = (kc * 4 + quad) ^ (row & 7);
                b[nt] = *(const s16x8*)&Bs[row * 64 + c8 * 8];
            }
#pragma unroll
            for (int mt = 0; mt < 4; ++mt)
#pragma unroll
                for (int nt = 0; nt < 4; ++nt)
                    acc[mt][nt] = __builtin_amdgcn_mfma_f32_16x16x32_bf16(
                        a[mt], b[nt], acc[mt][nt], 0, 0, 0);
        }
    }

    __syncthreads();
#pragma unroll
    for (int nt = 0; nt < 4; ++nt) {
        float bvv = bias[nBase + nw + nt * 16 + l15];
        int col = nw + nt * 16 + l15;
#pragma unroll
        for (int mt = 0; mt < 4; ++mt)
#pragma unroll
            for (int r = 0; r < 4; ++r) {
                int row = mw + mt * 16 + quad * 4 + r;
                short v = f2bf(acc[mt][nt][r] + bvv);
                if (z == 2) smem[col * 144 + row] = v;     // transposed for frag-major store
                else        smem[row * 128 + col] = v;
            }
    }
    __syncthreads();
    if (z == 2) {
#pragma unroll
        for (int i = 0; i < 8; ++i) {
            int f = t + i * 256;
            int d = f >> 4, kb8 = (f & 15) * 8;            // n-local d, 8-key group
            uint4 val = *(const uint4*)&smem[d * 144 + kb8];
            int m0 = mBase + kb8, n = nBase + d;
            int B = m0 >> 5, key0 = m0 & 31, hh = n >> 6, dd = n & 63;
            size_t dst = ((size_t)(B * NUM_HEADS + hh) * 2048) +
                         (size_t)((dd >> 4) * 512 + (key0 >> 3) * 128 + (dd & 15) * 8);
            *(uint4*)&outp[dst] = val;
        }
    } else {
#pragma unroll
        for (int i = 0; i < 8; ++i) {
            int f = t + i * 256;
            int row = f >> 4, c8 = (f & 15) * 8;
            uint4 val = *(const uint4*)&smem[row * 128 + c8];
            int m = mBase + row, n = nBase + c8;
            size_t dst = (((size_t)(m >> 5) * NUM_HEADS + (n >> 6)) * SLOT_LEN + (m & 31)) * 64 + (n & 63);
            *(uint4*)&outp[dst] = val;
        }
    }
}

// ---------------------------------------------------------------------------
// Attention v4: ONE BLOCK per (B,h); 4 waves split 21 chunks.
// Fragment-direct K/V: QK B-frag = 8 consecutive d -> 16B loads straight from
// ROW-MAJOR K (cache0 bf16 cast, self kbw, cache1 f32 converted in-reg).
// PV B-frag = 8 consecutive keys -> 16B loads from FRAG-MAJOR V (cache0 via
// prep_v0, self via qkv z==2 epilogue). No K/V LDS staging except cache1's V.
// LDS/wave: V_c1 4KB + P 2KB; merge scratch aliased -> block 33792 B.
// Chunk map: wave w: cache0 {4w..4w+3} + cache1 {16+w}; wave0 also self(20).
// ---------------------------------------------------------------------------
__global__ __launch_bounds__(256) void attn_mfma(
    const short* __restrict__ qb, const short* __restrict__ kbuf,
    const short* __restrict__ vbuf,
    const short* __restrict__ k0c, const short* __restrict__ v0f,
    const float* __restrict__ c1k, const float* __restrict__ c1v,
    const float* __restrict__ mask, float* __restrict__ out)
{
    __shared__ __align__(16) float smf[8448];     // 33792 B, aliased below
    short* sm16 = (short*)smf;

    const int t = threadIdx.x, lane = t & 63, w = t >> 6;
    const int task = blockIdx.x;                  // < 2880
    const int B = task / 12, h = task % 12;
    const int l15 = lane & 15, quad = lane >> 4;

    const short* qp   = qb  + (size_t)(B * NUM_HEADS + h) * 2048;
    const short* kspF = kbuf + (size_t)(B * NUM_HEADS + h) * 2048;   // row-major
    const short* vspF = vbuf + (size_t)(B * NUM_HEADS + h) * 2048;   // frag-major
    const short* k0p  = k0c + (size_t)((B & 7) * NUM_HEADS + h) * LEN0 * 64;  // row-major
    const short* v0p  = v0f + (size_t)((B & 7) * NUM_HEADS + h) * LEN0 * 64;  // frag-major
    const float* k1p  = c1k + (size_t)(B * NUM_HEADS + h) * LEN1 * 64;
    const float* v1p  = c1v + (size_t)(B * NUM_HEADS + h) * LEN1 * 64;
    const float* mp   = mask + (size_t)B * KTOT;

    short (*V)[32] = (short(*)[32])(sm16 + w * 3072);          // cache1 V staging
    short (*P)[32] = (short(*)[32])(sm16 + w * 3072 + 2048);

    const int skey = lane >> 4;               // f32 V staging: lane -> (key%4, c4)
    const int sc4 = (lane & 15) << 2;

    const float LOG2E = 1.4426950408889634f;
    const float SCL   = 0.125f * 1.4426950408889634f;

    // Q fragments
    s16x8 qf[2][2];
#pragma unroll
    for (int qh = 0; qh < 2; ++qh)
#pragma unroll
        for (int kc = 0; kc < 2; ++kc)
            qf[qh][kc] = *(const s16x8*)&qp[(qh * 16 + l15) * 64 + kc * 32 + quad * 8];

    const f32x4 z4 = {0.f, 0.f, 0.f, 0.f};
    f32x4 o[2][4];
    float lpart[2][4];
#pragma unroll
    for (int qh = 0; qh < 2; ++qh) {
#pragma unroll
        for (int dq = 0; dq < 4; ++dq) o[qh][dq] = z4;
#pragma unroll
        for (int r = 0; r < 4; ++r) lpart[qh][r] = 0.f;
    }

    // ---- compute pieces ---------------------------------------------------
    auto qk_mm = [&](const s16x8* kf, f32x4 (*s)[2]) {
#pragma unroll
        for (int qh = 0; qh < 2; ++qh)
#pragma unroll
            for (int kh = 0; kh < 2; ++kh) s[qh][kh] = z4;
#pragma unroll
        for (int kh = 0; kh < 2; ++kh)
#pragma unroll
            for (int qh = 0; qh < 2; ++qh) {
                s[qh][kh] = __builtin_amdgcn_mfma_f32_16x16x32_bf16(qf[qh][0], kf[kh * 2 + 0], s[qh][kh], 0, 0, 0);
                s[qh][kh] = __builtin_amdgcn_mfma_f32_16x16x32_bf16(qf[qh][1], kf[kh * 2 + 1], s[qh][kh], 0, 0, 0);
            }
    };
    auto exp_p = [&](f32x4 (*s)[2], float mv0, float mv1) {
#pragma unroll
        for (int qh = 0; qh < 2; ++qh)
#pragma unroll
            for (int kh = 0; kh < 2; ++kh) {
                float mv = kh ? mv1 : mv0;
#pragma unroll
                for (int r = 0; r < 4; ++r) {
                    float p = exp2f(fmaf(s[qh][kh][r], SCL, mv));
                    lpart[qh][r] += p;
                    int prow = qh * 16 + quad * 4 + r;
                    int pswz = ((kh * 2 + (l15 >> 3)) ^ ((prow >> 1) & 3)) * 8 + (l15 & 7);
                    P[prow][pswz] = f2bf(p);
                }
            }
    };
    auto pv_reg = [&](const s16x8* vf) {
#pragma unroll
        for (int qh = 0; qh < 2; ++qh) {
            int prow2 = qh * 16 + l15;
            int pg = (quad ^ ((l15 >> 1) & 3)) * 8;
            s16x4 plo = *(const s16x4*)&P[prow2][pg];
            s16x4 phi = *(const s16x4*)&P[prow2][pg + 4];
            s16x8 pf = __builtin_shufflevector(plo, phi, 0, 1, 2, 3, 4, 5, 6, 7);
#pragma unroll
            for (int dq = 0; dq < 4; ++dq)
                o[qh][dq] = __builtin_amdgcn_mfma_f32_16x16x32_bf16(pf, vf[dq], o[qh][dq], 0, 0, 0);
        }
    };
    auto pv_lds = [&]() {
#pragma unroll
        for (int qh = 0; qh < 2; ++qh) {
            int prow2 = qh * 16 + l15;
            int pg = (quad ^ ((l15 >> 1) & 3)) * 8;
            s16x4 plo = *(const s16x4*)&P[prow2][pg];
            s16x4 phi = *(const s16x4*)&P[prow2][pg + 4];
            s16x8 pf = __builtin_shufflevector(plo, phi, 0, 1, 2, 3, 4, 5, 6, 7);
#pragma unroll
            for (int dq = 0; dq < 4; ++dq) {
                int vrow = dq * 16 + l15;
                s16x8 vf = *(const s16x8*)&V[vrow][(quad ^ ((l15 >> 1) & 3)) * 8];
                o[qh][dq] = __builtin_amdgcn_mfma_f32_16x16x32_bf16(pf, vf, o[qh][dq], 0, 0, 0);
            }
        }
    };

    // ---- fast chunks: cache0 {4w..4w+3} (+ self on wave 0) ----------------
    const int c0base = w * 4;
    const int nfast = (w == 0) ? 5 : 4;

    auto load_kf = [&](int i, s16x8* kf) {    // row-major K -> QK B-frags
        const short* kb = (i < 4) ? (k0p + (size_t)(c0base + i) * 2048) : kspF;
#pragma unroll
        for (int f = 0; f < 4; ++f) {
            int kh = f >> 1, kc = f & 1;
            kf[f] = *(const s16x8*)&kb[(kh * 16 + l15) * 64 + kc * 32 + quad * 8];
        }
    };
    auto load_vf = [&](int i, s16x8* vf) {    // frag-major V -> PV B-frags
        const short* vb = (i < 4) ? (v0p + (size_t)(c0base + i) * 2048) : vspF;
#pragma unroll
        for (int dq = 0; dq < 4; ++dq)
            vf[dq] = *(const s16x8*)&vb[(dq * 64 + lane) * 8];
    };
    auto mchunk = [&](int i) { return (i < 4) ? (c0base + i) : 20; };

    s16x8 kf[4], vf[4];
    float mv0n, mv1n;
    load_kf(0, kf);
    load_vf(0, vf);
    { int mc = mchunk(0); mv0n = mp[mc * 32 + l15] * LOG2E; mv1n = mp[mc * 32 + 16 + l15] * LOG2E; }

    for (int i = 0; i < nfast; ++i) {
        float mv0 = mv0n, mv1 = mv1n;
        f32x4 s[2][2];
        qk_mm(kf, s);
        if (i + 1 < nfast) {                  // reload kf: covered by exp+PV
            load_kf(i + 1, kf);
            int mc = mchunk(i + 1);
            mv0n = mp[mc * 32 + l15] * LOG2E;
            mv1n = mp[mc * 32 + 16 + l15] * LOG2E;
        }
        exp_p(s, mv0, mv1);
        pv_reg(vf);
        if (i + 1 < nfast) load_vf(i + 1, vf); // covered by next QK+exp
    }

    // ---- cache1 chunk (16+w): K in-reg f32->bf16 frags; V via LDS ---------
    {
        const float* sk = k1p + w * 2048;
        const float* sv = v1p + w * 2048;
        float4 vvr[8];
#pragma unroll
        for (int i = 0; i < 8; ++i)
            vvr[i] = *(const float4*)&sv[(i * 4 + skey) * 64 + sc4];
        s16x8 kc1[4];
#pragma unroll
        for (int f = 0; f < 4; ++f) {
            int kh = f >> 1, kc = f & 1;
            const float* kfp = &sk[(kh * 16 + l15) * 64 + kc * 32 + quad * 8];
            float4 lo = *(const float4*)kfp;
            float4 hi = *(const float4*)(kfp + 4);
            kc1[f] = {f2bf(lo.x), f2bf(lo.y), f2bf(lo.z), f2bf(lo.w),
                      f2bf(hi.x), f2bf(hi.y), f2bf(hi.z), f2bf(hi.w)};
        }
        int mc = 16 + w;
        float mv0 = mp[mc * 32 + l15] * LOG2E;
        float mv1 = mp[mc * 32 + 16 + l15] * LOG2E;
        f32x4 s[2][2];
        qk_mm(kc1, s);
        exp_p(s, mv0, mv1);
#pragma unroll
        for (int i = 0; i < 8; ++i) {         // scatter V f32 -> swizzled LDS
            int key = i * 4 + skey;
            int kg = key >> 3, ks = key & 7;
#pragma unroll
            for (int j = 0; j < 4; ++j) {
                int rowv = sc4 + j;
                float fv = (j == 0) ? vvr[i].x : (j == 1) ? vvr[i].y : (j == 2) ? vvr[i].z : vvr[i].w;
                V[rowv][(kg ^ ((rowv >> 1) & 3)) * 8 + ks] = f2bf(fv);
            }
        }
        pv_lds();
    }

    // ---- merge: sum 4 wave-partials (o, l) via aliased LDS scratch --------
    float lred[2][4];
#pragma unroll
    for (int qh = 0; qh < 2; ++qh)
#pragma unroll
        for (int r = 0; r < 4; ++r) {
            float l = lpart[qh][r];
            l += __shfl_xor(l, 1);
            l += __shfl_xor(l, 2);
            l += __shfl_xor(l, 4);
            l += __shfl_xor(l, 8);
            lred[qh][r] = l;
        }

    __syncthreads();                           // everyone done with V/P
#pragma unroll
    for (int qh = 0; qh < 2; ++qh)
#pragma unroll
        for (int dq = 0; dq < 4; ++dq)
#pragma unroll
            for (int r = 0; r < 4; ++r) {
                int row = qh * 16 + quad * 4 + r, col = dq * 16 + l15;
                smf[w * 2048 + row * 64 + col] = o[qh][dq][r];
            }
    if (l15 == 0) {
#pragma unroll
        for (int qh = 0; qh < 2; ++qh)
#pragma unroll
            for (int r = 0; r < 4; ++r)
                smf[8192 + w * 32 + qh * 16 + quad * 4 + r] = lred[qh][r];
    }
    __syncthreads();

    {
        int row = t >> 3, c8 = (t & 7) * 8;
        float lt = smf[8192 + row] + smf[8192 + 32 + row] +
                   smf[8192 + 64 + row] + smf[8192 + 96 + row];
        float inv = 1.f / lt;
        float4 o0, o1;
#pragma unroll
        for (int j = 0; j < 4; ++j) {
            int col = c8 + j;
            o0[j] = (smf[row * 64 + col] + smf[2048 + row * 64 + col] +
                     smf[4096 + row * 64 + col] + smf[6144 + row * 64 + col]) * inv;
        }
#pragma unroll
        for (int j = 0; j < 4; ++j) {
            int col = c8 + 4 + j;
            o1[j] = (smf[row * 64 + col] + smf[2048 + row * 64 + col] +
                     smf[4096 + row * 64 + col] + smf[6144 + row * 64 + col]) * inv;
        }
        float* op = &out[((size_t)B * SLOT_LEN + row) * HIDDEN + h * 64 + c8];
        *(float4*)op = o0;
        *(float4*)(op + 4) = o1;
    }
}

// ---------------------------------------------------------------------------
extern "C" void kernel_launch(void* const* d_in, const int* in_sizes, int n_in,
                              void* d_out, int out_size, void* d_ws, size_t ws_size,
                              hipStream_t stream) {
    const float* hs   = (const float*)d_in[0];
    const float* mask = (const float*)d_in[1];
    const float* c0k  = (const float*)d_in[2];
    const float* c0v  = (const float*)d_in[3];
    const float* c1k  = (const float*)d_in[4];
    const float* c1v  = (const float*)d_in[5];
    const float* Wq   = (const float*)d_in[6];
    const float* bq   = (const float*)d_in[7];
    const float* Wk   = (const float*)d_in[8];
    const float* bk   = (const float*)d_in[9];
    const float* Wv   = (const float*)d_in[10];
    const float* bv   = (const float*)d_in[11];
    float* out = (float*)d_out;

    short* hsb = (short*)d_ws;
    short* WtA = hsb + (size_t)M_TOK * HIDDEN;
    short* qb  = WtA + (size_t)3 * HIDDEN * HIDDEN;
    short* kbw = qb + (size_t)M_TOK * HIDDEN;
    short* vbw = kbw + (size_t)M_TOK * HIDDEN;
    // cache0 pre-pass buffers: reuse hsb+WtA region (dead after qkv_mfma).
    // k0c (row-major bf16) + v0f (frag-major bf16): 2 x 3,145,728 shorts
    // fit in hsb(5,898,240) + WtA(1,769,472).
    short* k0c = (short*)d_ws;
    short* v0f = k0c + (size_t)BS * NUM_HEADS * LEN0 * HEAD_DIM;

    cast_hs<<<(M_TOK * HIDDEN / 4 + 255) / 256, 256, 0, stream>>>(hs, hsb, M_TOK * HIDDEN / 4);
    cast_w_t<<<dim3(24, 24, 3), 256, 0, stream>>>(Wq, Wk, Wv, WtA);
    qkv_mfma<<<dim3(HIDDEN / 128, M_TOK / 128, 3), 256, 0, stream>>>(
        hsb, WtA, bq, bk, bv, qb, kbw, vbw);
    // pre-pass AFTER qkv (workspace reuse): flat-cast K0, frag-transpose V0
    {
        int n4 = BS * NUM_HEADS * LEN0 * HEAD_DIM / 4;   // 786432
        cast_hs<<<(n4 + 255) / 256, 256, 0, stream>>>(c0k, k0c, n4);
        prep_v0<<<BS * NUM_HEADS * (LEN0 / 32), 256, 0, stream>>>(c0v, v0f);
    }
    attn_mfma<<<FULL * NUM_HEADS, 256, 0, stream>>>(qb, kbw, vbw, k0c, v0f, c1k, c1v, mask, out);
}

// Round 7
// 350.641 us; speedup vs baseline: 4.7017x; 1.0262x over previous
//
#include <hip/hip_runtime.h>
#include <math.h>

#define NUM_HEADS 12
#define HEAD_DIM  64
#define HIDDEN    768
#define BS        8
#define FULL      240
#define SLOT_LEN  32
#define LEN0      512
#define LEN1      128
#define KTOT      672
#define M_TOK     (FULL * SLOT_LEN)   // 7680

typedef float f32x4 __attribute__((ext_vector_type(4)));
typedef short s16x8 __attribute__((ext_vector_type(8)));
typedef short s16x4 __attribute__((ext_vector_type(4)));

__device__ __forceinline__ short f2bf(float x) {
    unsigned u = __float_as_uint(x);
    unsigned r = (u + 0x7fffu + ((u >> 16) & 1u)) >> 16;
    return (short)r;
}

// async global->LDS, 16B per lane; lds base must be wave-uniform
__device__ __forceinline__ void gll16(const short* g, short* l) {
    __builtin_amdgcn_global_load_lds(
        (const __attribute__((address_space(1))) unsigned int*)g,
        (__attribute__((address_space(3))) unsigned int*)l, 16, 0, 0);
}

// ---------------------------------------------------------------------------
__global__ __launch_bounds__(256) void cast_hs(const float* __restrict__ in,
                                               short* __restrict__ out, int n4) {
    int i = blockIdx.x * 256 + threadIdx.x;
    if (i < n4) {
        float4 v = ((const float4*)in)[i];
        s16x4 o = {f2bf(v.x), f2bf(v.y), f2bf(v.z), f2bf(v.w)};
        ((s16x4*)out)[i] = o;
    }
}

// ---------------------------------------------------------------------------
// Fused cache0 pre-pass (single launch):
//  blocks [0,3072):  flat bf16 cast of cache0_key (row-major, 786432 float4s)
//  blocks [3072,3264): cache0_value -> bf16 FRAG-MAJOR per 32-key chunk:
//    v0f[chunk*2048 + (dq*64+quad*16+l15)*8 + j] = V[key=quad*8+j][d=dq*16+l15]
// ---------------------------------------------------------------------------
__global__ __launch_bounds__(256) void prep_c0(const float* __restrict__ k0,
                                               const float* __restrict__ v0,
                                               short* __restrict__ k0c,
                                               short* __restrict__ v0f) {
    __shared__ float tile[32][65];
    const int t = threadIdx.x;
    if (blockIdx.x < 3072) {
        int i = blockIdx.x * 256 + t;            // < 786432
        float4 v = ((const float4*)k0)[i];
        s16x4 o = {f2bf(v.x), f2bf(v.y), f2bf(v.z), f2bf(v.w)};
        ((s16x4*)k0c)[i] = o;
        return;
    }
    const size_t base = (size_t)(blockIdx.x - 3072) * 2048;
#pragma unroll
    for (int i = 0; i < 2; ++i) {
        int f = t + i * 256;                     // float4 unit, 512 total
        int kr = f >> 4, d4 = (f & 15) * 4;
        float4 v = *(const float4*)&v0[base + kr * 64 + d4];
        tile[kr][d4 + 0] = v.x; tile[kr][d4 + 1] = v.y;
        tile[kr][d4 + 2] = v.z; tile[kr][d4 + 3] = v.w;
    }
    __syncthreads();
    const int dq = t >> 6, lane = t & 63;
    const int quad = lane >> 4, l15 = lane & 15;
    s16x8 o = {f2bf(tile[quad * 8 + 0][dq * 16 + l15]),
               f2bf(tile[quad * 8 + 1][dq * 16 + l15]),
               f2bf(tile[quad * 8 + 2][dq * 16 + l15]),
               f2bf(tile[quad * 8 + 3][dq * 16 + l15]),
               f2bf(tile[quad * 8 + 4][dq * 16 + l15]),
               f2bf(tile[quad * 8 + 5][dq * 16 + l15]),
               f2bf(tile[quad * 8 + 6][dq * 16 + l15]),
               f2bf(tile[quad * 8 + 7][dq * 16 + l15])};
    *(s16x8*)&v0f[base + (size_t)t * 8] = o;
}

// ---------------------------------------------------------------------------
__global__ __launch_bounds__(256) void cast_w_t(const float* __restrict__ Wq,
                                                const float* __restrict__ Wk,
                                                const float* __restrict__ Wv,
                                                short* __restrict__ WtAll) {
    const float* W = (blockIdx.z == 0) ? Wq : (blockIdx.z == 1) ? Wk : Wv;
    short* Wt = WtAll + (size_t)blockIdx.z * HIDDEN * HIDDEN;
    __shared__ __align__(16) float tile[32][33];
    const int kb0 = blockIdx.y * 32, nb0 = blockIdx.x * 32;
    const int r = threadIdx.x >> 3, c4 = (threadIdx.x & 7) * 4;
    float4 v = *(const float4*)&W[(size_t)(kb0 + r) * HIDDEN + nb0 + c4];
    tile[r][c4 + 0] = v.x; tile[r][c4 + 1] = v.y;
    tile[r][c4 + 2] = v.z; tile[r][c4 + 3] = v.w;
    __syncthreads();
    s16x4 o = {f2bf(tile[c4 + 0][r]), f2bf(tile[c4 + 1][r]),
               f2bf(tile[c4 + 2][r]), f2bf(tile[c4 + 3][r])};
    *(s16x4*)&Wt[(size_t)(nb0 + r) * HIDDEN + kb0 + c4] = o;
}

// ---------------------------------------------------------------------------
// QKV GEMM: 128x128 tile, BK=64, global_load_lds(16B) staging, XOR-swizzled
// unpadded LDS. Epilogue: z==0 (Q) and z==1 (K) write row-major [B,h][key][d];
// z==2 (V) writes FRAG-MAJOR per (B,h) via a transposed smem pass.
// ---------------------------------------------------------------------------
__global__ __launch_bounds__(256) void qkv_mfma(
    const short* __restrict__ hsb, const short* __restrict__ WtAll,
    const float* __restrict__ bq, const float* __restrict__ bk,
    const float* __restrict__ bv,
    short* __restrict__ qo, short* __restrict__ ko, short* __restrict__ vo)
{
    const int z = blockIdx.z;
    const short* Wt = WtAll + (size_t)z * HIDDEN * HIDDEN;
    const float* bias = (z == 0) ? bq : (z == 1) ? bk : bv;
    short* outp = (z == 0) ? qo : (z == 1) ? ko : vo;

    __shared__ __align__(16) short smem[128 * 144];   // 36.9KB; K-loop uses first 32KB
    short* As = smem;
    short* Bs = smem + 128 * 64;

    const int t = threadIdx.x;
    const int lane = t & 63, w = t >> 6;
    const int l15 = lane & 15, quad = lane >> 4;
    const int mBase = blockIdx.y * 128, nBase = blockIdx.x * 128;
    const int mw = (w & 1) * 64, nw = (w >> 1) * 64;

    const int srow_in = lane >> 3;
    const int scol8 = (lane & 7) ^ srow_in;

    f32x4 acc[4][4];
    const f32x4 z4 = {0.f, 0.f, 0.f, 0.f};
#pragma unroll
    for (int i = 0; i < 4; ++i)
#pragma unroll
        for (int j = 0; j < 4; ++j) acc[i][j] = z4;

    for (int kb = 0; kb < HIDDEN; kb += 64) {
        __syncthreads();
#pragma unroll
        for (int j = 0; j < 4; ++j) {
            int row = w * 32 + j * 8 + srow_in;
            gll16(&hsb[(size_t)(mBase + row) * HIDDEN + kb + scol8 * 8],
                  &As[(w * 32 + j * 8) * 64]);
            gll16(&Wt[(size_t)(nBase + row) * HIDDEN + kb + scol8 * 8],
                  &Bs[(w * 32 + j * 8) * 64]);
        }
        __syncthreads();
#pragma unroll
        for (int kc = 0; kc < 2; ++kc) {
            s16x8 a[4], b[4];
#pragma unroll
            for (int mt = 0; mt < 4; ++mt) {
                int row = mw + mt * 16 + l15;
                int c8 = (kc * 4 + quad) ^ (row & 7);
                a[mt] = *(const s16x8*)&As[row * 64 + c8 * 8];
            }
#pragma unroll
            for (int nt = 0; nt < 4; ++nt) {
                int row = nw + nt * 16 + l15;
                int c8 = (kc * 4 + quad) ^ (row & 7);
                b[nt] = *(const s16x8*)&Bs[row * 64 + c8 * 8];
            }
#pragma unroll
            for (int mt = 0; mt < 4; ++mt)
#pragma unroll
                for (int nt = 0; nt < 4; ++nt)
                    acc[mt][nt] = __builtin_amdgcn_mfma_f32_16x16x32_bf16(
                        a[mt], b[nt], acc[mt][nt], 0, 0, 0);
        }
    }

    __syncthreads();
#pragma unroll
    for (int nt = 0; nt < 4; ++nt) {
        float bvv = bias[nBase + nw + nt * 16 + l15];
        int col = nw + nt * 16 + l15;
#pragma unroll
        for (int mt = 0; mt < 4; ++mt)
#pragma unroll
            for (int r = 0; r < 4; ++r) {
                int row = mw + mt * 16 + quad * 4 + r;
                short v = f2bf(acc[mt][nt][r] + bvv);
                if (z == 2) smem[col * 144 + row] = v;     // transposed for frag-major store
                else        smem[row * 128 + col] = v;
            }
    }
    __syncthreads();
    if (z == 2) {
#pragma unroll
        for (int i = 0; i < 8; ++i) {
            int f = t + i * 256;
            int d = f >> 4, kb8 = (f & 15) * 8;            // n-local d, 8-key group
            uint4 val = *(const uint4*)&smem[d * 144 + kb8];
            int m0 = mBase + kb8, n = nBase + d;
            int B = m0 >> 5, key0 = m0 & 31, hh = n >> 6, dd = n & 63;
            size_t dst = ((size_t)(B * NUM_HEADS + hh) * 2048) +
                         (size_t)((dd >> 4) * 512 + (key0 >> 3) * 128 + (dd & 15) * 8);
            *(uint4*)&outp[dst] = val;
        }
    } else {
#pragma unroll
        for (int i = 0; i < 8; ++i) {
            int f = t + i * 256;
            int row = f >> 4, c8 = (f & 15) * 8;
            uint4 val = *(const uint4*)&smem[row * 128 + c8];
            int m = mBase + row, n = nBase + c8;
            size_t dst = (((size_t)(m >> 5) * NUM_HEADS + (n >> 6)) * SLOT_LEN + (m & 31)) * 64 + (n & 63);
            *(uint4*)&outp[dst] = val;
        }
    }
}

// ---------------------------------------------------------------------------
// Attention v5: ONE BLOCK per (B,h); 4 waves split 21 chunks.
// Frag-direct K/V (row-major K -> QK B-frag; frag-major V -> PV B-frag).
// NEW: 2-deep A/B register prefetch (kfA/kfB + vfA/vfB, static names only):
// K-frags reloaded right after their QK, V-frags right after their PV, so
// each load has ~1.5 chunk-computes of latency coverage. R6 measured only
// ~400 B/wave in flight (1.8 TB/s effective) -> depth, not pattern, is the
// limiter. VGPR budget: 88 + 32 = ~120, must stay <= 128.
// Chunk map: wave w: cache0 {4w..4w+3} + cache1 {16+w}; wave0 also self(20).
// ---------------------------------------------------------------------------
__global__ __launch_bounds__(256) void attn_mfma(
    const short* __restrict__ qb, const short* __restrict__ kbuf,
    const short* __restrict__ vbuf,
    const short* __restrict__ k0c, const short* __restrict__ v0f,
    const float* __restrict__ c1k, const float* __restrict__ c1v,
    const float* __restrict__ mask, float* __restrict__ out)
{
    __shared__ __align__(16) float smf[8448];     // 33792 B, aliased below
    short* sm16 = (short*)smf;

    const int t = threadIdx.x, lane = t & 63, w = t >> 6;
    const int task = blockIdx.x;                  // < 2880
    const int B = task / 12, h = task % 12;
    const int l15 = lane & 15, quad = lane >> 4;

    const short* qp   = qb  + (size_t)(B * NUM_HEADS + h) * 2048;
    const short* kspF = kbuf + (size_t)(B * NUM_HEADS + h) * 2048;   // row-major
    const short* vspF = vbuf + (size_t)(B * NUM_HEADS + h) * 2048;   // frag-major
    const short* k0p  = k0c + (size_t)((B & 7) * NUM_HEADS + h) * LEN0 * 64;  // row-major
    const short* v0p  = v0f + (size_t)((B & 7) * NUM_HEADS + h) * LEN0 * 64;  // frag-major
    const float* k1p  = c1k + (size_t)(B * NUM_HEADS + h) * LEN1 * 64;
    const float* v1p  = c1v + (size_t)(B * NUM_HEADS + h) * LEN1 * 64;
    const float* mp   = mask + (size_t)B * KTOT;

    short (*V)[32] = (short(*)[32])(sm16 + w * 3072);          // cache1 V staging
    short (*P)[32] = (short(*)[32])(sm16 + w * 3072 + 2048);

    const int skey = lane >> 4;               // f32 V staging: lane -> (key%4, c4)
    const int sc4 = (lane & 15) << 2;

    const float LOG2E = 1.4426950408889634f;
    const float SCL   = 0.125f * 1.4426950408889634f;

    // Q fragments
    s16x8 qf[2][2];
#pragma unroll
    for (int qh = 0; qh < 2; ++qh)
#pragma unroll
        for (int kc = 0; kc < 2; ++kc)
            qf[qh][kc] = *(const s16x8*)&qp[(qh * 16 + l15) * 64 + kc * 32 + quad * 8];

    const f32x4 z4 = {0.f, 0.f, 0.f, 0.f};
    f32x4 o[2][4];
    float lpart[2][4];
#pragma unroll
    for (int qh = 0; qh < 2; ++qh) {
#pragma unroll
        for (int dq = 0; dq < 4; ++dq) o[qh][dq] = z4;
#pragma unroll
        for (int r = 0; r < 4; ++r) lpart[qh][r] = 0.f;
    }

    // ---- compute pieces ---------------------------------------------------
    auto qk_mm = [&](const s16x8* kf, f32x4 (*s)[2]) {
#pragma unroll
        for (int qh = 0; qh < 2; ++qh)
#pragma unroll
            for (int kh = 0; kh < 2; ++kh) s[qh][kh] = z4;
#pragma unroll
        for (int kh = 0; kh < 2; ++kh)
#pragma unroll
            for (int qh = 0; qh < 2; ++qh) {
                s[qh][kh] = __builtin_amdgcn_mfma_f32_16x16x32_bf16(qf[qh][0], kf[kh * 2 + 0], s[qh][kh], 0, 0, 0);
                s[qh][kh] = __builtin_amdgcn_mfma_f32_16x16x32_bf16(qf[qh][1], kf[kh * 2 + 1], s[qh][kh], 0, 0, 0);
            }
    };
    auto exp_p = [&](f32x4 (*s)[2], float mv0, float mv1) {
#pragma unroll
        for (int qh = 0; qh < 2; ++qh)
#pragma unroll
            for (int kh = 0; kh < 2; ++kh) {
                float mv = kh ? mv1 : mv0;
#pragma unroll
                for (int r = 0; r < 4; ++r) {
                    float p = exp2f(fmaf(s[qh][kh][r], SCL, mv));
                    lpart[qh][r] += p;
                    int prow = qh * 16 + quad * 4 + r;
                    int pswz = ((kh * 2 + (l15 >> 3)) ^ ((prow >> 1) & 3)) * 8 + (l15 & 7);
                    P[prow][pswz] = f2bf(p);
                }
            }
    };
    auto pv_reg = [&](const s16x8* vf) {
#pragma unroll
        for (int qh = 0; qh < 2; ++qh) {
            int prow2 = qh * 16 + l15;
            int pg = (quad ^ ((l15 >> 1) & 3)) * 8;
            s16x4 plo = *(const s16x4*)&P[prow2][pg];
            s16x4 phi = *(const s16x4*)&P[prow2][pg + 4];
            s16x8 pf = __builtin_shufflevector(plo, phi, 0, 1, 2, 3, 4, 5, 6, 7);
#pragma unroll
            for (int dq = 0; dq < 4; ++dq)
                o[qh][dq] = __builtin_amdgcn_mfma_f32_16x16x32_bf16(pf, vf[dq], o[qh][dq], 0, 0, 0);
        }
    };
    auto pv_lds = [&]() {
#pragma unroll
        for (int qh = 0; qh < 2; ++qh) {
            int prow2 = qh * 16 + l15;
            int pg = (quad ^ ((l15 >> 1) & 3)) * 8;
            s16x4 plo = *(const s16x4*)&P[prow2][pg];
            s16x4 phi = *(const s16x4*)&P[prow2][pg + 4];
            s16x8 pf = __builtin_shufflevector(plo, phi, 0, 1, 2, 3, 4, 5, 6, 7);
#pragma unroll
            for (int dq = 0; dq < 4; ++dq) {
                int vrow = dq * 16 + l15;
                s16x8 vf = *(const s16x8*)&V[vrow][(quad ^ ((l15 >> 1) & 3)) * 8];
                o[qh][dq] = __builtin_amdgcn_mfma_f32_16x16x32_bf16(pf, vf, o[qh][dq], 0, 0, 0);
            }
        }
    };

    // ---- frag loaders -----------------------------------------------------
    auto ldK = [&](const short* kb, s16x8* kf) {  // row-major K -> QK B-frags
#pragma unroll
        for (int f = 0; f < 4; ++f) {
            int kh = f >> 1, kc = f & 1;
            kf[f] = *(const s16x8*)&kb[(kh * 16 + l15) * 64 + kc * 32 + quad * 8];
        }
    };
    auto ldV = [&](const short* vb, s16x8* vf) {  // frag-major V -> PV B-frags
#pragma unroll
        for (int dq = 0; dq < 4; ++dq)
            vf[dq] = *(const s16x8*)&vb[(dq * 64 + lane) * 8];
    };

    // ---- pipelined step: QK -> (reload K) -> exp -> PV -> (reload V) ------
    auto step = [&](s16x8* kf, s16x8* vf, float m0, float m1,
                    const short* nkb, const short* nvb,
                    float* nm0, float* nm1, int nmc) {
        f32x4 s[2][2];
        qk_mm(kf, s);
        if (nkb) {
            ldK(nkb, kf);
            *nm0 = mp[nmc * 32 + l15] * LOG2E;
            *nm1 = mp[nmc * 32 + 16 + l15] * LOG2E;
        }
        exp_p(s, m0, m1);
        pv_reg(vf);
        if (nvb) ldV(nvb, vf);
    };

    // ---- fast chunks: cache0 {4w..4w+3} (+ self on wave 0), 2-deep A/B ----
    const int c0base = w * 4;
    const short* kcb = k0p + (size_t)c0base * 2048;
    const short* vcb = v0p + (size_t)c0base * 2048;

    s16x8 kfA[4], vfA[4], kfB[4], vfB[4];
    float mA0, mA1, mB0, mB1;

    ldK(kcb, kfA);             ldV(vcb, vfA);
    mA0 = mp[c0base * 32 + l15] * LOG2E;
    mA1 = mp[c0base * 32 + 16 + l15] * LOG2E;
    ldK(kcb + 2048, kfB);      ldV(vcb + 2048, vfB);
    mB0 = mp[(c0base + 1) * 32 + l15] * LOG2E;
    mB1 = mp[(c0base + 1) * 32 + 16 + l15] * LOG2E;

    // it0: compute chunk c0base+0, prefetch c0base+2 into A
    step(kfA, vfA, mA0, mA1, kcb + 2 * 2048, vcb + 2 * 2048, &mA0, &mA1, c0base + 2);
    // it1: compute chunk c0base+1, prefetch c0base+3 into B
    step(kfB, vfB, mB0, mB1, kcb + 3 * 2048, vcb + 3 * 2048, &mB0, &mB1, c0base + 3);
    if (w == 0) {
        // it2: compute c0base+2, prefetch SELF into A
        step(kfA, vfA, mA0, mA1, kspF, vspF, &mA0, &mA1, 20);
        // it3: compute c0base+3
        step(kfB, vfB, mB0, mB1, nullptr, nullptr, nullptr, nullptr, 0);
        // it4: compute self
        step(kfA, vfA, mA0, mA1, nullptr, nullptr, nullptr, nullptr, 0);
    } else {
        step(kfA, vfA, mA0, mA1, nullptr, nullptr, nullptr, nullptr, 0);
        step(kfB, vfB, mB0, mB1, nullptr, nullptr, nullptr, nullptr, 0);
    }

    // ---- cache1 chunk (16+w): K in-reg f32->bf16 frags; V via LDS ---------
    {
        const float* sk = k1p + w * 2048;
        const float* sv = v1p + w * 2048;
        float4 vvr[8];
#pragma unroll
        for (int i = 0; i < 8; ++i)
            vvr[i] = *(const float4*)&sv[(i * 4 + skey) * 64 + sc4];
        s16x8 kc1[4];
#pragma unroll
        for (int f = 0; f < 4; ++f) {
            int kh = f >> 1, kc = f & 1;
            const float* kfp = &sk[(kh * 16 + l15) * 64 + kc * 32 + quad * 8];
            float4 lo = *(const float4*)kfp;
            float4 hi = *(const float4*)(kfp + 4);
            kc1[f] = {f2bf(lo.x), f2bf(lo.y), f2bf(lo.z), f2bf(lo.w),
                      f2bf(hi.x), f2bf(hi.y), f2bf(hi.z), f2bf(hi.w)};
        }
        int mc = 16 + w;
        float mv0 = mp[mc * 32 + l15] * LOG2E;
        float mv1 = mp[mc * 32 + 16 + l15] * LOG2E;
        f32x4 s[2][2];
        qk_mm(kc1, s);
        exp_p(s, mv0, mv1);
#pragma unroll
        for (int i = 0; i < 8; ++i) {         // scatter V f32 -> swizzled LDS
            int key = i * 4 + skey;
            int kg = key >> 3, ks = key & 7;
#pragma unroll
            for (int j = 0; j < 4; ++j) {
                int rowv = sc4 + j;
                float fv = (j == 0) ? vvr[i].x : (j == 1) ? vvr[i].y : (j == 2) ? vvr[i].z : vvr[i].w;
                V[rowv][(kg ^ ((rowv >> 1) & 3)) * 8 + ks] = f2bf(fv);
            }
        }
        pv_lds();
    }

    // ---- merge: sum 4 wave-partials (o, l) via aliased LDS scratch --------
    float lred[2][4];
#pragma unroll
    for (int qh = 0; qh < 2; ++qh)
#pragma unroll
        for (int r = 0; r < 4; ++r) {
            float l = lpart[qh][r];
            l += __shfl_xor(l, 1);
            l += __shfl_xor(l, 2);
            l += __shfl_xor(l, 4);
            l += __shfl_xor(l, 8);
            lred[qh][r] = l;
        }

    __syncthreads();                           // everyone done with V/P
#pragma unroll
    for (int qh = 0; qh < 2; ++qh)
#pragma unroll
        for (int dq = 0; dq < 4; ++dq)
#pragma unroll
            for (int r = 0; r < 4; ++r) {
                int row = qh * 16 + quad * 4 + r, col = dq * 16 + l15;
                smf[w * 2048 + row * 64 + col] = o[qh][dq][r];
            }
    if (l15 == 0) {
#pragma unroll
        for (int qh = 0; qh < 2; ++qh)
#pragma unroll
            for (int r = 0; r < 4; ++r)
                smf[8192 + w * 32 + qh * 16 + quad * 4 + r] = lred[qh][r];
    }
    __syncthreads();

    {
        int row = t >> 3, c8 = (t & 7) * 8;
        float lt = smf[8192 + row] + smf[8192 + 32 + row] +
                   smf[8192 + 64 + row] + smf[8192 + 96 + row];
        float inv = 1.f / lt;
        float4 o0, o1;
#pragma unroll
        for (int j = 0; j < 4; ++j) {
            int col = c8 + j;
            o0[j] = (smf[row * 64 + col] + smf[2048 + row * 64 + col] +
                     smf[4096 + row * 64 + col] + smf[6144 + row * 64 + col]) * inv;
        }
#pragma unroll
        for (int j = 0; j < 4; ++j) {
            int col = c8 + 4 + j;
            o1[j] = (smf[row * 64 + col] + smf[2048 + row * 64 + col] +
                     smf[4096 + row * 64 + col] + smf[6144 + row * 64 + col]) * inv;
        }
        float* op = &out[((size_t)B * SLOT_LEN + row) * HIDDEN + h * 64 + c8];
        *(float4*)op = o0;
        *(float4*)(op + 4) = o1;
    }
}

// ---------------------------------------------------------------------------
extern "C" void kernel_launch(void* const* d_in, const int* in_sizes, int n_in,
                              void* d_out, int out_size, void* d_ws, size_t ws_size,
                              hipStream_t stream) {
    const float* hs   = (const float*)d_in[0];
    const float* mask = (const float*)d_in[1];
    const float* c0k  = (const float*)d_in[2];
    const float* c0v  = (const float*)d_in[3];
    const float* c1k  = (const float*)d_in[4];
    const float* c1v  = (const float*)d_in[5];
    const float* Wq   = (const float*)d_in[6];
    const float* bq   = (const float*)d_in[7];
    const float* Wk   = (const float*)d_in[8];
    const float* bk   = (const float*)d_in[9];
    const float* Wv   = (const float*)d_in[10];
    const float* bv   = (const float*)d_in[11];
    float* out = (float*)d_out;

    short* hsb = (short*)d_ws;
    short* WtA = hsb + (size_t)M_TOK * HIDDEN;
    short* qb  = WtA + (size_t)3 * HIDDEN * HIDDEN;
    short* kbw = qb + (size_t)M_TOK * HIDDEN;
    short* vbw = kbw + (size_t)M_TOK * HIDDEN;
    // cache0 pre-pass buffers: reuse hsb+WtA region (dead after qkv_mfma).
    short* k0c = (short*)d_ws;
    short* v0f = k0c + (size_t)BS * NUM_HEADS * LEN0 * HEAD_DIM;

    cast_hs<<<(M_TOK * HIDDEN / 4 + 255) / 256, 256, 0, stream>>>(hs, hsb, M_TOK * HIDDEN / 4);
    cast_w_t<<<dim3(24, 24, 3), 256, 0, stream>>>(Wq, Wk, Wv, WtA);
    qkv_mfma<<<dim3(HIDDEN / 128, M_TOK / 128, 3), 256, 0, stream>>>(
        hsb, WtA, bq, bk, bv, qb, kbw, vbw);
    // fused pre-pass AFTER qkv (workspace reuse): K0 cast + V0 frag-transpose
    prep_c0<<<3072 + BS * NUM_HEADS * (LEN0 / 32), 256, 0, stream>>>(c0k, c0v, k0c, v0f);
    attn_mfma<<<FULL * NUM_HEADS, 256, 0, stream>>>(qb, kbw, vbw, k0c, v0f, c1k, c1v, mask, out);
}